// Round 5
// baseline (485.119 us; speedup 1.0000x reference)
//
#include <hip/hip_runtime.h>
#include <hip/hip_bf16.h>
#include <hip/hip_fp16.h>

// ---------------------------------------------------------------------------
// GCN link predictor, fp16 intermediate buffers (fp32 accumulate everywhere):
//   dinv[v] = rsqrt(indeg(v)+1)
//   g  = (X @ W) * dinv[row]            (fused in GEMM epilogue, stored fp16)
//   z  = relu(dinv[v]*(g[v] + sum_{s->v} g[s]) + b)   (CSR gather, fused)
//   out[e] = dot(z2[s_e], z2[d_e])      (fp32 accumulate)
// CSR built per call via bucketed counting sort (R4: naive scatter was
// write-allocate-bound, 107 MB writeback for 6.4 MB of payload):
//   bucket = dst >> 8 (256 nodes/bucket). LDS-binned scatter with bulk range
//   claims -> contiguous runs; final per-bucket scatter confines random
//   writes to a 16 KB window per CU so L2 lines fill before writeback.
// ---------------------------------------------------------------------------

typedef _Float16 half8 __attribute__((ext_vector_type(8)));
typedef _Float16 half4 __attribute__((ext_vector_type(4)));

#define BK_SHIFT 8
#define BK_EDGES 4096   // edges per block in binning kernels

__global__ __launch_bounds__(256) void k_zero(int* __restrict__ p, int n) {
    int i = blockIdx.x * 256 + threadIdx.x;
    if (i < n) p[i] = 0;
}

__global__ __launch_bounds__(256) void k_hist(const int* __restrict__ dst,
                                              int* __restrict__ cnt, int E) {
    int e = blockIdx.x * 256 + threadIdx.x;
    if (e < E) atomicAdd(&cnt[dst[e]], 1);
}

// block-level inclusive scan -> exclusive row_start + block sums
__global__ __launch_bounds__(1024) void k_scan1(const int* __restrict__ cnt,
                                                int* __restrict__ row_start,
                                                int* __restrict__ bsum, int n) {
    __shared__ int sh[1024];
    int tid = threadIdx.x;
    int i = blockIdx.x * 1024 + tid;
    int v = (i < n) ? cnt[i] : 0;
    sh[tid] = v;
    __syncthreads();
    for (int off = 1; off < 1024; off <<= 1) {
        int t = (tid >= off) ? sh[tid - off] : 0;
        __syncthreads();
        sh[tid] += t;
        __syncthreads();
    }
    if (i < n) row_start[i] = sh[tid] - v;
    if (tid == 1023) bsum[blockIdx.x] = sh[tid];
}

// exclusive scan of block sums (nb <= 1024)
__global__ __launch_bounds__(1024) void k_scan2(int* __restrict__ bsum, int nb) {
    __shared__ int sh[1024];
    int tid = threadIdx.x;
    int v = (tid < nb) ? bsum[tid] : 0;
    sh[tid] = v;
    __syncthreads();
    for (int off = 1; off < 1024; off <<= 1) {
        int t = (tid >= off) ? sh[tid - off] : 0;
        __syncthreads();
        sh[tid] += t;
        __syncthreads();
    }
    if (tid < nb) bsum[tid] = sh[tid] - v;
}

// add block offsets + compute dinv = rsqrt(deg+1)  (deg includes self loop)
__global__ __launch_bounds__(256) void k_scan3(int* __restrict__ row_start,
                                               const int* __restrict__ bsum,
                                               const int* __restrict__ cnt,
                                               float* __restrict__ dinv, int n) {
    int i = blockIdx.x * 256 + threadIdx.x;
    if (i < n) {
        row_start[i] += bsum[i >> 10];
        dinv[i] = rsqrtf((float)cnt[i] + 1.0f);
    }
}

// ---- bucket histogram: LDS-accumulated, one global atomic per block/bucket
__global__ __launch_bounds__(256) void k_bhist(const int* __restrict__ dst,
                                               int* __restrict__ bcnt,
                                               int E, int nbk) {
    __shared__ int lcnt[1024];
    int tid = threadIdx.x;
    for (int b = tid; b < nbk; b += 256) lcnt[b] = 0;
    __syncthreads();
    int e0 = blockIdx.x * BK_EDGES;
#pragma unroll
    for (int k = 0; k < BK_EDGES / 256; ++k) {
        int e = e0 + k * 256 + tid;
        if (e < E) atomicAdd(&lcnt[dst[e] >> BK_SHIFT], 1);
    }
    __syncthreads();
    for (int b = tid; b < nbk; b += 256)
        if (lcnt[b]) atomicAdd(&bcnt[b], lcnt[b]);
}

// ---- exclusive scan of bucket counts; bstart[nbk] = E; bfill = bstart copy
__global__ __launch_bounds__(1024) void k_bscan(const int* __restrict__ bcnt,
                                                int* __restrict__ bstart,
                                                int* __restrict__ bfill,
                                                int nbk, int E) {
    __shared__ int sh[1024];
    int tid = threadIdx.x;
    int v = (tid < nbk) ? bcnt[tid] : 0;
    sh[tid] = v;
    __syncthreads();
    for (int off = 1; off < 1024; off <<= 1) {
        int t = (tid >= off) ? sh[tid - off] : 0;
        __syncthreads();
        sh[tid] += t;
        __syncthreads();
    }
    if (tid < nbk) {
        int ex = sh[tid] - v;
        bstart[tid] = ex;
        bfill[tid] = ex;
    }
    if (tid == 0) bstart[nbk] = E;
}

// ---- LDS-binned scatter of (src,dst) pairs into bucket-sorted order.
// Per block: local count -> wave0 scan + bulk global claims -> local scatter
// into LDS staging -> linear copy-out (contiguous runs per bucket).
__global__ __launch_bounds__(256) void k_bscatter(const int* __restrict__ src,
                                                  const int* __restrict__ dst,
                                                  int* __restrict__ bfill,
                                                  int2* __restrict__ pairs,
                                                  int E, int nbk) {
    __shared__ int lcnt[1024];   // working: count, then fill cursor
    __shared__ int lbase[1024];  // local exclusive scan (const after phase 2)
    __shared__ int gbase[1024];  // claimed global base per bucket
    __shared__ int2 stage[BK_EDGES];
    int tid = threadIdx.x;
    int e0 = blockIdx.x * BK_EDGES;
    int nloc = E - e0; if (nloc > BK_EDGES) nloc = BK_EDGES;

    for (int b = tid; b < nbk; b += 256) lcnt[b] = 0;
    __syncthreads();

    int d[BK_EDGES / 256];
#pragma unroll
    for (int k = 0; k < BK_EDGES / 256; ++k) {
        int e = e0 + k * 256 + tid;
        if (e < E) {
            d[k] = dst[e];
            atomicAdd(&lcnt[d[k] >> BK_SHIFT], 1);
        } else d[k] = -1;
    }
    __syncthreads();

    // wave 0: exclusive scan of lcnt[0..nbk) + bulk claims
    if (tid < 64) {
        int gpb = (nbk + 63) >> 6;  // buckets per lane (<=16)
        int vv[16];
        int run = 0;
        for (int t = 0; t < gpb; ++t) {
            int b = tid * gpb + t;
            int c = (b < nbk) ? lcnt[b] : 0;
            vv[t] = run;       // exclusive within lane group
            run += c;
        }
        // wave exclusive scan of per-lane sums
        int x = run;
        for (int off = 1; off < 64; off <<= 1) {
            int y = __shfl_up(x, off, 64);
            if (tid >= off) x += y;
        }
        int ex = x - run;
        for (int t = 0; t < gpb; ++t) {
            int b = tid * gpb + t;
            if (b < nbk) {
                int lb = ex + vv[t];
                lbase[b] = lb;
                int c = lcnt[b];
                gbase[b] = c ? atomicAdd(&bfill[b], c) : 0;
            }
        }
    }
    __syncthreads();
    // reset working cursor to lbase
    for (int b = tid; b < nbk; b += 256) lcnt[b] = lbase[b];
    __syncthreads();

    // local scatter into staging
#pragma unroll
    for (int k = 0; k < BK_EDGES / 256; ++k) {
        int e = e0 + k * 256 + tid;
        if (e < E) {
            int b = d[k] >> BK_SHIFT;
            int lp = atomicAdd(&lcnt[b], 1);
            int2 p; p.x = src[e]; p.y = d[k];
            stage[lp] = p;
        }
    }
    __syncthreads();

    // copy-out: consecutive j in same bucket -> consecutive global addresses
    for (int j = tid; j < nloc; j += 256) {
        int2 p = stage[j];
        int b = p.y >> BK_SHIFT;
        pairs[gbase[b] + (j - lbase[b])] = p;
    }
}

// ---- final CSR scatter: one block per bucket; random writes confined to
// the bucket's ~16 KB srcs window (single CU -> L2 lines fill fully).
__global__ __launch_bounds__(256) void k_cscatter(const int2* __restrict__ pairs,
                                                  const int* __restrict__ bstart,
                                                  const int* __restrict__ row_start,
                                                  int* __restrict__ srcs) {
    __shared__ int lfill[1 << BK_SHIFT];
    int tid = threadIdx.x;
    int b = blockIdx.x;
    for (int i = tid; i < (1 << BK_SHIFT); i += 256) lfill[i] = 0;
    __syncthreads();
    int beg = bstart[b], end = bstart[b + 1];
    for (int i = beg + tid; i < end; i += 256) {
        int2 p = pairs[i];
        int loc = atomicAdd(&lfill[p.y & ((1 << BK_SHIFT) - 1)], 1);
        srcs[row_start[p.y] + loc] = p.x;
    }
}

// ---------------------------------------------------------------------------
// GEMM: G[r][c] = dinv[r] * sum_k A[r][k]*W[k][c]    (N x 128) @ (128 x 128)
// A is fp32 (layer 1: x) or fp16 (layer 2: z1). Output G is fp16.
// ---------------------------------------------------------------------------
template <typename AT>
__global__ __launch_bounds__(256, 4) void k_gemm_scale(const AT* __restrict__ X,
                                                       const float* __restrict__ W,
                                                       const float* __restrict__ dinv,
                                                       _Float16* __restrict__ G, int n) {
    __shared__ float Wl[32 * 128];
    const int tid = threadIdx.x;
    const int colgrp = tid & 15;
    const int rowgrp = tid >> 4;
    const int r0 = blockIdx.x * 64 + rowgrp * 4;
    const int c0 = colgrp * 4;

    const AT* Xr[4];
#pragma unroll
    for (int i = 0; i < 4; ++i) {
        int r = r0 + i;
        if (r >= n) r = n - 1;
        Xr[i] = X + (size_t)r * 128;
    }

    float acc[4][8] = {};

    auto loadA = [](const AT* p) -> float4 {
        if constexpr (sizeof(AT) == 4) {
            return *(const float4*)p;
        } else {
            half4 h = *(const half4*)p;
            float4 f;
            f.x = (float)h[0]; f.y = (float)h[1];
            f.z = (float)h[2]; f.w = (float)h[3];
            return f;
        }
    };

    for (int kc = 0; kc < 128; kc += 32) {
        {
            const float4* W4 = (const float4*)(W + (size_t)kc * 128);
            float4* Wl4 = (float4*)Wl;
#pragma unroll
            for (int it = 0; it < 4; ++it)
                Wl4[it * 256 + tid] = W4[it * 256 + tid];
        }
        __syncthreads();

        float4 a_cur[4], a_nxt[4];
#pragma unroll
        for (int i = 0; i < 4; ++i) a_cur[i] = loadA(Xr[i] + kc);

#pragma unroll 1
        for (int k4 = 0; k4 < 28; k4 += 4) {
#pragma unroll
            for (int i = 0; i < 4; ++i) a_nxt[i] = loadA(Xr[i] + kc + k4 + 4);
#pragma unroll
            for (int kk = 0; kk < 4; ++kk) {
                float4 b0 = *(const float4*)(Wl + (k4 + kk) * 128 + c0);
                float4 b1 = *(const float4*)(Wl + (k4 + kk) * 128 + c0 + 64);
#pragma unroll
                for (int i = 0; i < 4; ++i) {
                    float av = (kk == 0) ? a_cur[i].x : (kk == 1) ? a_cur[i].y
                             : (kk == 2) ? a_cur[i].z : a_cur[i].w;
                    acc[i][0] += av * b0.x; acc[i][1] += av * b0.y;
                    acc[i][2] += av * b0.z; acc[i][3] += av * b0.w;
                    acc[i][4] += av * b1.x; acc[i][5] += av * b1.y;
                    acc[i][6] += av * b1.z; acc[i][7] += av * b1.w;
                }
            }
#pragma unroll
            for (int i = 0; i < 4; ++i) a_cur[i] = a_nxt[i];
        }
#pragma unroll
        for (int kk = 0; kk < 4; ++kk) {
            float4 b0 = *(const float4*)(Wl + (28 + kk) * 128 + c0);
            float4 b1 = *(const float4*)(Wl + (28 + kk) * 128 + c0 + 64);
#pragma unroll
            for (int i = 0; i < 4; ++i) {
                float av = (kk == 0) ? a_cur[i].x : (kk == 1) ? a_cur[i].y
                         : (kk == 2) ? a_cur[i].z : a_cur[i].w;
                acc[i][0] += av * b0.x; acc[i][1] += av * b0.y;
                acc[i][2] += av * b0.z; acc[i][3] += av * b0.w;
                acc[i][4] += av * b1.x; acc[i][5] += av * b1.y;
                acc[i][6] += av * b1.z; acc[i][7] += av * b1.w;
            }
        }
        __syncthreads();
    }

#pragma unroll
    for (int i = 0; i < 4; ++i) {
        int r = r0 + i;
        if (r < n) {
            float dv = dinv[r];
            half4 o0, o1;
#pragma unroll
            for (int j = 0; j < 4; ++j) {
                o0[j] = (_Float16)(acc[i][j] * dv);
                o1[j] = (_Float16)(acc[i][4 + j] * dv);
            }
            *(half4*)(G + (size_t)r * 128 + c0) = o0;
            *(half4*)(G + (size_t)r * 128 + c0 + 64) = o1;
        }
    }
}

// ---------------------------------------------------------------------------
// Gather-aggregate + bias + relu. 16 lanes per node (half8 over 128 dims),
// 16 nodes per 256-thread block. acc init = g[v] (self loop), fp32 accum.
// ---------------------------------------------------------------------------
__global__ __launch_bounds__(256) void k_gather_relu(const _Float16* __restrict__ G,
                                                     const int* __restrict__ srcs,
                                                     const int* __restrict__ row_start,
                                                     const int* __restrict__ cnt,
                                                     const float* __restrict__ dinv,
                                                     const float* __restrict__ bias,
                                                     _Float16* __restrict__ Z, int n) {
    int v = blockIdx.x * 16 + (threadIdx.x >> 4);
    int lane = threadIdx.x & 15;
    if (v >= n) return;
    const half8* G8 = (const half8*)G;

    half8 self = G8[(size_t)v * 16 + lane];
    float acc[8], acc2[8];
#pragma unroll
    for (int j = 0; j < 8; ++j) { acc[j] = (float)self[j]; acc2[j] = 0.f; }

    int beg = row_start[v], deg = cnt[v];
    int e = 0;
    for (; e + 3 < deg; e += 4) {
        int s0 = srcs[beg + e];
        int s1 = srcs[beg + e + 1];
        int s2 = srcs[beg + e + 2];
        int s3 = srcs[beg + e + 3];
        half8 t0 = G8[(size_t)s0 * 16 + lane];
        half8 t1 = G8[(size_t)s1 * 16 + lane];
        half8 t2 = G8[(size_t)s2 * 16 + lane];
        half8 t3 = G8[(size_t)s3 * 16 + lane];
#pragma unroll
        for (int j = 0; j < 8; ++j) {
            acc[j]  += (float)t0[j] + (float)t1[j];
            acc2[j] += (float)t2[j] + (float)t3[j];
        }
    }
    for (; e < deg; ++e) {
        int s0 = srcs[beg + e];
        half8 t0 = G8[(size_t)s0 * 16 + lane];
#pragma unroll
        for (int j = 0; j < 8; ++j) acc[j] += (float)t0[j];
    }

    float dv = dinv[v];
    const float4* b4 = (const float4*)bias;
    float4 bb0 = b4[lane * 2], bb1 = b4[lane * 2 + 1];
    float bf[8] = {bb0.x, bb0.y, bb0.z, bb0.w, bb1.x, bb1.y, bb1.z, bb1.w};
    half8 zo;
#pragma unroll
    for (int j = 0; j < 8; ++j) {
        float z = dv * (acc[j] + acc2[j]) + bf[j];
        zo[j] = (_Float16)fmaxf(z, 0.f);
    }
    ((half8*)Z)[(size_t)v * 16 + lane] = zo;
}

// ---------------------------------------------------------------------------
// Decode: out[e] = dot(Z[s_e], Z[d_e]) over 128 dims (fp16 rows, fp32 accum).
// ---------------------------------------------------------------------------
__global__ __launch_bounds__(256) void k_decode(const _Float16* __restrict__ Z,
                                                const int* __restrict__ eli,
                                                float* __restrict__ out, int el) {
    int sub = threadIdx.x >> 4, lane = threadIdx.x & 15;
    int e = blockIdx.x * 16 + sub;
    if (e >= el) return;
    int s = eli[e], d = eli[el + e];
    const half8* Z8 = (const half8*)Z;
    half8 a = Z8[(size_t)s * 16 + lane];
    half8 b = Z8[(size_t)d * 16 + lane];
    float dot = 0.f;
#pragma unroll
    for (int j = 0; j < 8; ++j) dot += (float)a[j] * (float)b[j];
#pragma unroll
    for (int off = 8; off; off >>= 1) dot += __shfl_down(dot, off, 16);
    if (lane == 0) out[e] = dot;
}

extern "C" void kernel_launch(void* const* d_in, const int* in_sizes, int n_in,
                              void* d_out, int out_size, void* d_ws, size_t ws_size,
                              hipStream_t stream) {
    const float* x  = (const float*)d_in[0];
    const int*  ei  = (const int*)d_in[1];
    const int*  eli = (const int*)d_in[2];
    const float* W1 = (const float*)d_in[3];
    const float* b1 = (const float*)d_in[4];
    const float* W2 = (const float*)d_in[5];
    const float* b2 = (const float*)d_in[6];
    float* out = (float*)d_out;

    const int N  = in_sizes[0] / 128;
    const int E  = in_sizes[1] / 2;
    const int EL = in_sizes[2] / 2;
    const int* src = ei;
    const int* dst = ei + E;
    const int NBK = (N + 255) >> BK_SHIFT;   // 391 for N=100000 (<=1024)

    char* ws = (char*)d_ws;
    size_t off = 0;
    auto alloc = [&](size_t bytes) -> void* {
        void* p = ws + off;
        off += bytes;
        off = (off + 255) & ~(size_t)255;
        return p;
    };
    int*       cnt       = (int*)alloc((size_t)N * 4);
    int*       bcnt      = (int*)alloc(4096);          // contiguous after cnt: one zero pass
    int*       row_start = (int*)alloc((size_t)N * 4);
    float*     dinv      = (float*)alloc((size_t)N * 4);
    int*       bsum      = (int*)alloc(4096);
    int*       bstart    = (int*)alloc(4100);
    int*       bfill     = (int*)alloc(4096);
    int*       srcs      = (int*)alloc((size_t)E * 4);
    int2*      pairs     = (int2*)alloc((size_t)E * 8);
    _Float16*  buf0      = (_Float16*)alloc((size_t)N * 128 * 2);  // G (pre-agg)
    _Float16*  buf1      = (_Float16*)alloc((size_t)N * 128 * 2);  // Z (post-agg)

    const int nb = (N + 1023) / 1024;
    const int zspan = (int)(((char*)bcnt - (char*)cnt) / 4) + 1024;  // cnt..bcnt

    k_zero<<<(zspan + 255) / 256, 256, 0, stream>>>(cnt, zspan);
    k_hist<<<(E + 255) / 256, 256, 0, stream>>>(dst, cnt, E);
    k_scan1<<<nb, 1024, 0, stream>>>(cnt, row_start, bsum, N);
    k_scan2<<<1, 1024, 0, stream>>>(bsum, nb);
    k_scan3<<<(N + 255) / 256, 256, 0, stream>>>(row_start, bsum, cnt, dinv, N);

    const int ebk = (E + BK_EDGES - 1) / BK_EDGES;
    k_bhist<<<ebk, 256, 0, stream>>>(dst, bcnt, E, NBK);
    k_bscan<<<1, 1024, 0, stream>>>(bcnt, bstart, bfill, NBK, E);
    k_bscatter<<<ebk, 256, 0, stream>>>(src, dst, bfill, pairs, E, NBK);
    k_cscatter<<<NBK, 256, 0, stream>>>(pairs, bstart, row_start, srcs);

    // layer 1: g1 = (x@W1)*dinv -> buf0 (fp16) ; z1 -> buf1 (fp16)
    k_gemm_scale<float><<<(N + 63) / 64, 256, 0, stream>>>(x, W1, dinv, buf0, N);
    k_gather_relu<<<(N + 15) / 16, 256, 0, stream>>>(buf0, srcs, row_start, cnt, dinv, b1, buf1, N);
    // layer 2: g2 = (z1@W2)*dinv -> buf0 ; z2 -> buf1
    k_gemm_scale<_Float16><<<(N + 63) / 64, 256, 0, stream>>>(buf1, W2, dinv, buf0, N);
    k_gather_relu<<<(N + 15) / 16, 256, 0, stream>>>(buf0, srcs, row_start, cnt, dinv, b2, buf1, N);
    // decode
    k_decode<<<(EL + 15) / 16, 256, 0, stream>>>(buf1, eli, out, EL);
}

// Round 6
// 484.158 us; speedup vs baseline: 1.0020x; 1.0020x over previous
//
#include <hip/hip_runtime.h>
#include <hip/hip_bf16.h>
#include <hip/hip_fp16.h>

// ---------------------------------------------------------------------------
// GCN link predictor, fp16 intermediate buffers (fp32 accumulate everywhere):
//   dinv[v] = rsqrt(indeg(v)+1)
//   g  = (X @ W) * dinv[row]            (fused in GEMM epilogue, stored fp16)
//   z  = relu(dinv[v]*(g[v] + sum_{s->v} g[s]) + b)   (CSR gather, fused)
//   out[e] = dot(z2[s_e], z2[d_e])      (fp32 accumulate)
// CSR built per call via bucketed counting sort (R4: naive scatter was
// write-allocate-bound: 1.6M random 4B stores -> 107 MB sector writeback).
// R5 lesson: 4096-edge bscatter blocks -> only 391 blocks (1.5/CU), grid-
// starved latency-bound (occupancy 13.7%, all pipes idle). R6: 2048-edge
// blocks (782, ~3/CU resident x 6 LDS-fit), full-block scan, fewer barriers.
// ---------------------------------------------------------------------------

typedef _Float16 half8 __attribute__((ext_vector_type(8)));
typedef _Float16 half4 __attribute__((ext_vector_type(4)));

#define BK_SHIFT 8
#define BH_EDGES 1024   // edges per block in bucket histogram
#define BSC_EDGES 2048  // edges per block in binning scatter

__global__ __launch_bounds__(256) void k_zero(int* __restrict__ p, int n) {
    int i = blockIdx.x * 256 + threadIdx.x;
    if (i < n) p[i] = 0;
}

__global__ __launch_bounds__(256) void k_hist(const int* __restrict__ dst,
                                              int* __restrict__ cnt, int E) {
    int e = blockIdx.x * 256 + threadIdx.x;
    if (e < E) atomicAdd(&cnt[dst[e]], 1);
}

// block-level inclusive scan -> exclusive row_start + block sums
__global__ __launch_bounds__(1024) void k_scan1(const int* __restrict__ cnt,
                                                int* __restrict__ row_start,
                                                int* __restrict__ bsum, int n) {
    __shared__ int sh[1024];
    int tid = threadIdx.x;
    int i = blockIdx.x * 1024 + tid;
    int v = (i < n) ? cnt[i] : 0;
    sh[tid] = v;
    __syncthreads();
    for (int off = 1; off < 1024; off <<= 1) {
        int t = (tid >= off) ? sh[tid - off] : 0;
        __syncthreads();
        sh[tid] += t;
        __syncthreads();
    }
    if (i < n) row_start[i] = sh[tid] - v;
    if (tid == 1023) bsum[blockIdx.x] = sh[tid];
}

// exclusive scan of block sums (nb <= 1024)
__global__ __launch_bounds__(1024) void k_scan2(int* __restrict__ bsum, int nb) {
    __shared__ int sh[1024];
    int tid = threadIdx.x;
    int v = (tid < nb) ? bsum[tid] : 0;
    sh[tid] = v;
    __syncthreads();
    for (int off = 1; off < 1024; off <<= 1) {
        int t = (tid >= off) ? sh[tid - off] : 0;
        __syncthreads();
        sh[tid] += t;
        __syncthreads();
    }
    if (tid < nb) bsum[tid] = sh[tid] - v;
}

// add block offsets + compute dinv = rsqrt(deg+1)  (deg includes self loop)
__global__ __launch_bounds__(256) void k_scan3(int* __restrict__ row_start,
                                               const int* __restrict__ bsum,
                                               const int* __restrict__ cnt,
                                               float* __restrict__ dinv, int n) {
    int i = blockIdx.x * 256 + threadIdx.x;
    if (i < n) {
        row_start[i] += bsum[i >> 10];
        dinv[i] = rsqrtf((float)cnt[i] + 1.0f);
    }
}

// ---- bucket histogram: LDS-accumulated, one global atomic per block/bucket
__global__ __launch_bounds__(256) void k_bhist(const int* __restrict__ dst,
                                               int* __restrict__ bcnt,
                                               int E, int nbk) {
    __shared__ int lcnt[1024];
    int tid = threadIdx.x;
    for (int b = tid; b < nbk; b += 256) lcnt[b] = 0;
    __syncthreads();
    int e0 = blockIdx.x * BH_EDGES;
#pragma unroll
    for (int k = 0; k < BH_EDGES / 256; ++k) {
        int e = e0 + k * 256 + tid;
        if (e < E) atomicAdd(&lcnt[dst[e] >> BK_SHIFT], 1);
    }
    __syncthreads();
    for (int b = tid; b < nbk; b += 256)
        if (lcnt[b]) atomicAdd(&bcnt[b], lcnt[b]);
}

// ---- exclusive scan of bucket counts; bstart[nbk] = E; bfill = bstart copy
__global__ __launch_bounds__(1024) void k_bscan(const int* __restrict__ bcnt,
                                                int* __restrict__ bstart,
                                                int* __restrict__ bfill,
                                                int nbk, int E) {
    __shared__ int sh[1024];
    int tid = threadIdx.x;
    int v = (tid < nbk) ? bcnt[tid] : 0;
    sh[tid] = v;
    __syncthreads();
    for (int off = 1; off < 1024; off <<= 1) {
        int t = (tid >= off) ? sh[tid - off] : 0;
        __syncthreads();
        sh[tid] += t;
        __syncthreads();
    }
    if (tid < nbk) {
        int ex = sh[tid] - v;
        bstart[tid] = ex;
        bfill[tid] = ex;
    }
    if (tid == 0) bstart[nbk] = E;
}

// ---- LDS-binned scatter of (src,dst) pairs into bucket-sorted order.
// Per block: local count -> full-block scan + bulk global claims -> local
// scatter into LDS staging -> linear copy-out (contiguous runs per bucket).
__global__ __launch_bounds__(256) void k_bscatter(const int* __restrict__ src,
                                                  const int* __restrict__ dst,
                                                  int* __restrict__ bfill,
                                                  int2* __restrict__ pairs,
                                                  int E, int nbk) {
    __shared__ int lcnt[1024];    // counts, then fill cursor (= lbase)
    __shared__ int delta[1024];   // gbase - lbase per bucket
    __shared__ int ssum[256];     // block-scan workspace
    __shared__ int2 stage[BSC_EDGES];
    int tid = threadIdx.x;
    int e0 = blockIdx.x * BSC_EDGES;
    int nloc = E - e0; if (nloc > BSC_EDGES) nloc = BSC_EDGES;

    for (int b = tid; b < nbk; b += 256) lcnt[b] = 0;
    __syncthreads();

    int d[BSC_EDGES / 256], s[BSC_EDGES / 256];
#pragma unroll
    for (int k = 0; k < BSC_EDGES / 256; ++k) {
        int e = e0 + k * 256 + tid;
        if (e < E) {
            d[k] = dst[e];
            s[k] = src[e];
            atomicAdd(&lcnt[d[k] >> BK_SHIFT], 1);
        } else d[k] = -1;
    }
    __syncthreads();

    // full-block exclusive scan over nbk buckets (each thread owns gpb)
    const int gpb = (nbk + 255) >> 8;   // <=4 for nbk<=1024
    int c[4], mysum = 0;
    for (int t = 0; t < gpb; ++t) {
        int b = tid * gpb + t;
        c[t] = (b < nbk) ? lcnt[b] : 0;
        mysum += c[t];
    }
    ssum[tid] = mysum;
    __syncthreads();
    for (int off = 1; off < 256; off <<= 1) {
        int t = (tid >= off) ? ssum[tid - off] : 0;
        __syncthreads();
        ssum[tid] += t;
        __syncthreads();
    }
    int base = ssum[tid] - mysum;  // exclusive prefix of this thread's group
    for (int t = 0; t < gpb; ++t) {
        int b = tid * gpb + t;
        if (b < nbk) {
            int g = c[t] ? atomicAdd(&bfill[b], c[t]) : 0;
            delta[b] = g - base;   // gbase - lbase
            lcnt[b] = base;        // cursor starts at lbase
            base += c[t];
        }
    }
    __syncthreads();

    // local scatter into staging (bucket-grouped within block)
#pragma unroll
    for (int k = 0; k < BSC_EDGES / 256; ++k) {
        if (d[k] >= 0) {
            int b = d[k] >> BK_SHIFT;
            int lp = atomicAdd(&lcnt[b], 1);
            int2 p; p.x = s[k]; p.y = d[k];
            stage[lp] = p;
        }
    }
    __syncthreads();

    // copy-out: consecutive j in same bucket -> consecutive global addresses
    for (int j = tid; j < nloc; j += 256) {
        int2 p = stage[j];
        pairs[delta[p.y >> BK_SHIFT] + j] = p;
    }
}

// ---- final CSR scatter: one block per bucket; random writes confined to
// the bucket's ~16 KB srcs window (single CU -> L2 lines fill fully).
__global__ __launch_bounds__(256) void k_cscatter(const int2* __restrict__ pairs,
                                                  const int* __restrict__ bstart,
                                                  const int* __restrict__ row_start,
                                                  int* __restrict__ srcs) {
    __shared__ int lfill[1 << BK_SHIFT];
    int tid = threadIdx.x;
    int b = blockIdx.x;
    for (int i = tid; i < (1 << BK_SHIFT); i += 256) lfill[i] = 0;
    __syncthreads();
    int beg = bstart[b], end = bstart[b + 1];
    for (int i = beg + tid; i < end; i += 256) {
        int2 p = pairs[i];
        int loc = atomicAdd(&lfill[p.y & ((1 << BK_SHIFT) - 1)], 1);
        srcs[row_start[p.y] + loc] = p.x;
    }
}

// ---------------------------------------------------------------------------
// GEMM: G[r][c] = dinv[r] * sum_k A[r][k]*W[k][c]    (N x 128) @ (128 x 128)
// A is fp32 (layer 1: x) or fp16 (layer 2: z1). Output G is fp16.
// ---------------------------------------------------------------------------
template <typename AT>
__global__ __launch_bounds__(256, 4) void k_gemm_scale(const AT* __restrict__ X,
                                                       const float* __restrict__ W,
                                                       const float* __restrict__ dinv,
                                                       _Float16* __restrict__ G, int n) {
    __shared__ float Wl[32 * 128];
    const int tid = threadIdx.x;
    const int colgrp = tid & 15;
    const int rowgrp = tid >> 4;
    const int r0 = blockIdx.x * 64 + rowgrp * 4;
    const int c0 = colgrp * 4;

    const AT* Xr[4];
#pragma unroll
    for (int i = 0; i < 4; ++i) {
        int r = r0 + i;
        if (r >= n) r = n - 1;
        Xr[i] = X + (size_t)r * 128;
    }

    float acc[4][8] = {};

    auto loadA = [](const AT* p) -> float4 {
        if constexpr (sizeof(AT) == 4) {
            return *(const float4*)p;
        } else {
            half4 h = *(const half4*)p;
            float4 f;
            f.x = (float)h[0]; f.y = (float)h[1];
            f.z = (float)h[2]; f.w = (float)h[3];
            return f;
        }
    };

    for (int kc = 0; kc < 128; kc += 32) {
        {
            const float4* W4 = (const float4*)(W + (size_t)kc * 128);
            float4* Wl4 = (float4*)Wl;
#pragma unroll
            for (int it = 0; it < 4; ++it)
                Wl4[it * 256 + tid] = W4[it * 256 + tid];
        }
        __syncthreads();

        float4 a_cur[4], a_nxt[4];
#pragma unroll
        for (int i = 0; i < 4; ++i) a_cur[i] = loadA(Xr[i] + kc);

#pragma unroll 1
        for (int k4 = 0; k4 < 28; k4 += 4) {
#pragma unroll
            for (int i = 0; i < 4; ++i) a_nxt[i] = loadA(Xr[i] + kc + k4 + 4);
#pragma unroll
            for (int kk = 0; kk < 4; ++kk) {
                float4 b0 = *(const float4*)(Wl + (k4 + kk) * 128 + c0);
                float4 b1 = *(const float4*)(Wl + (k4 + kk) * 128 + c0 + 64);
#pragma unroll
                for (int i = 0; i < 4; ++i) {
                    float av = (kk == 0) ? a_cur[i].x : (kk == 1) ? a_cur[i].y
                             : (kk == 2) ? a_cur[i].z : a_cur[i].w;
                    acc[i][0] += av * b0.x; acc[i][1] += av * b0.y;
                    acc[i][2] += av * b0.z; acc[i][3] += av * b0.w;
                    acc[i][4] += av * b1.x; acc[i][5] += av * b1.y;
                    acc[i][6] += av * b1.z; acc[i][7] += av * b1.w;
                }
            }
#pragma unroll
            for (int i = 0; i < 4; ++i) a_cur[i] = a_nxt[i];
        }
#pragma unroll
        for (int kk = 0; kk < 4; ++kk) {
            float4 b0 = *(const float4*)(Wl + (28 + kk) * 128 + c0);
            float4 b1 = *(const float4*)(Wl + (28 + kk) * 128 + c0 + 64);
#pragma unroll
            for (int i = 0; i < 4; ++i) {
                float av = (kk == 0) ? a_cur[i].x : (kk == 1) ? a_cur[i].y
                         : (kk == 2) ? a_cur[i].z : a_cur[i].w;
                acc[i][0] += av * b0.x; acc[i][1] += av * b0.y;
                acc[i][2] += av * b0.z; acc[i][3] += av * b0.w;
                acc[i][4] += av * b1.x; acc[i][5] += av * b1.y;
                acc[i][6] += av * b1.z; acc[i][7] += av * b1.w;
            }
        }
        __syncthreads();
    }

#pragma unroll
    for (int i = 0; i < 4; ++i) {
        int r = r0 + i;
        if (r < n) {
            float dv = dinv[r];
            half4 o0, o1;
#pragma unroll
            for (int j = 0; j < 4; ++j) {
                o0[j] = (_Float16)(acc[i][j] * dv);
                o1[j] = (_Float16)(acc[i][4 + j] * dv);
            }
            *(half4*)(G + (size_t)r * 128 + c0) = o0;
            *(half4*)(G + (size_t)r * 128 + c0 + 64) = o1;
        }
    }
}

// ---------------------------------------------------------------------------
// Gather-aggregate + bias + relu. 16 lanes per node (half8 over 128 dims),
// 16 nodes per 256-thread block. acc init = g[v] (self loop), fp32 accum.
// ---------------------------------------------------------------------------
__global__ __launch_bounds__(256) void k_gather_relu(const _Float16* __restrict__ G,
                                                     const int* __restrict__ srcs,
                                                     const int* __restrict__ row_start,
                                                     const int* __restrict__ cnt,
                                                     const float* __restrict__ dinv,
                                                     const float* __restrict__ bias,
                                                     _Float16* __restrict__ Z, int n) {
    int v = blockIdx.x * 16 + (threadIdx.x >> 4);
    int lane = threadIdx.x & 15;
    if (v >= n) return;
    const half8* G8 = (const half8*)G;

    half8 self = G8[(size_t)v * 16 + lane];
    float acc[8], acc2[8];
#pragma unroll
    for (int j = 0; j < 8; ++j) { acc[j] = (float)self[j]; acc2[j] = 0.f; }

    int beg = row_start[v], deg = cnt[v];
    int e = 0;
    for (; e + 3 < deg; e += 4) {
        int s0 = srcs[beg + e];
        int s1 = srcs[beg + e + 1];
        int s2 = srcs[beg + e + 2];
        int s3 = srcs[beg + e + 3];
        half8 t0 = G8[(size_t)s0 * 16 + lane];
        half8 t1 = G8[(size_t)s1 * 16 + lane];
        half8 t2 = G8[(size_t)s2 * 16 + lane];
        half8 t3 = G8[(size_t)s3 * 16 + lane];
#pragma unroll
        for (int j = 0; j < 8; ++j) {
            acc[j]  += (float)t0[j] + (float)t1[j];
            acc2[j] += (float)t2[j] + (float)t3[j];
        }
    }
    for (; e < deg; ++e) {
        int s0 = srcs[beg + e];
        half8 t0 = G8[(size_t)s0 * 16 + lane];
#pragma unroll
        for (int j = 0; j < 8; ++j) acc[j] += (float)t0[j];
    }

    float dv = dinv[v];
    const float4* b4 = (const float4*)bias;
    float4 bb0 = b4[lane * 2], bb1 = b4[lane * 2 + 1];
    float bf[8] = {bb0.x, bb0.y, bb0.z, bb0.w, bb1.x, bb1.y, bb1.z, bb1.w};
    half8 zo;
#pragma unroll
    for (int j = 0; j < 8; ++j) {
        float z = dv * (acc[j] + acc2[j]) + bf[j];
        zo[j] = (_Float16)fmaxf(z, 0.f);
    }
    ((half8*)Z)[(size_t)v * 16 + lane] = zo;
}

// ---------------------------------------------------------------------------
// Decode: out[e] = dot(Z[s_e], Z[d_e]) over 128 dims (fp16 rows, fp32 accum).
// ---------------------------------------------------------------------------
__global__ __launch_bounds__(256) void k_decode(const _Float16* __restrict__ Z,
                                                const int* __restrict__ eli,
                                                float* __restrict__ out, int el) {
    int sub = threadIdx.x >> 4, lane = threadIdx.x & 15;
    int e = blockIdx.x * 16 + sub;
    if (e >= el) return;
    int s = eli[e], d = eli[el + e];
    const half8* Z8 = (const half8*)Z;
    half8 a = Z8[(size_t)s * 16 + lane];
    half8 b = Z8[(size_t)d * 16 + lane];
    float dot = 0.f;
#pragma unroll
    for (int j = 0; j < 8; ++j) dot += (float)a[j] * (float)b[j];
#pragma unroll
    for (int off = 8; off; off >>= 1) dot += __shfl_down(dot, off, 16);
    if (lane == 0) out[e] = dot;
}

extern "C" void kernel_launch(void* const* d_in, const int* in_sizes, int n_in,
                              void* d_out, int out_size, void* d_ws, size_t ws_size,
                              hipStream_t stream) {
    const float* x  = (const float*)d_in[0];
    const int*  ei  = (const int*)d_in[1];
    const int*  eli = (const int*)d_in[2];
    const float* W1 = (const float*)d_in[3];
    const float* b1 = (const float*)d_in[4];
    const float* W2 = (const float*)d_in[5];
    const float* b2 = (const float*)d_in[6];
    float* out = (float*)d_out;

    const int N  = in_sizes[0] / 128;
    const int E  = in_sizes[1] / 2;
    const int EL = in_sizes[2] / 2;
    const int* src = ei;
    const int* dst = ei + E;
    const int NBK = (N + 255) >> BK_SHIFT;   // 391 for N=100000 (<=1024)

    char* ws = (char*)d_ws;
    size_t off = 0;
    auto alloc = [&](size_t bytes) -> void* {
        void* p = ws + off;
        off += bytes;
        off = (off + 255) & ~(size_t)255;
        return p;
    };
    int*       cnt       = (int*)alloc((size_t)N * 4);
    int*       bcnt      = (int*)alloc(4096);          // contiguous after cnt: one zero pass
    int*       row_start = (int*)alloc((size_t)N * 4);
    float*     dinv      = (float*)alloc((size_t)N * 4);
    int*       bsum      = (int*)alloc(4096);
    int*       bstart    = (int*)alloc(4100);
    int*       bfill     = (int*)alloc(4096);
    int*       srcs      = (int*)alloc((size_t)E * 4);
    int2*      pairs     = (int2*)alloc((size_t)E * 8);
    _Float16*  buf0      = (_Float16*)alloc((size_t)N * 128 * 2);  // G (pre-agg)
    _Float16*  buf1      = (_Float16*)alloc((size_t)N * 128 * 2);  // Z (post-agg)

    const int nb = (N + 1023) / 1024;
    const int zspan = (int)(((char*)bcnt - (char*)cnt) / 4) + 1024;  // cnt..bcnt

    k_zero<<<(zspan + 255) / 256, 256, 0, stream>>>(cnt, zspan);
    k_hist<<<(E + 255) / 256, 256, 0, stream>>>(dst, cnt, E);
    k_scan1<<<nb, 1024, 0, stream>>>(cnt, row_start, bsum, N);
    k_scan2<<<1, 1024, 0, stream>>>(bsum, nb);
    k_scan3<<<(N + 255) / 256, 256, 0, stream>>>(row_start, bsum, cnt, dinv, N);

    k_bhist<<<(E + BH_EDGES - 1) / BH_EDGES, 256, 0, stream>>>(dst, bcnt, E, NBK);
    k_bscan<<<1, 1024, 0, stream>>>(bcnt, bstart, bfill, NBK, E);
    k_bscatter<<<(E + BSC_EDGES - 1) / BSC_EDGES, 256, 0, stream>>>(src, dst, bfill, pairs, E, NBK);
    k_cscatter<<<NBK, 256, 0, stream>>>(pairs, bstart, row_start, srcs);

    // layer 1: g1 = (x@W1)*dinv -> buf0 (fp16) ; z1 -> buf1 (fp16)
    k_gemm_scale<float><<<(N + 63) / 64, 256, 0, stream>>>(x, W1, dinv, buf0, N);
    k_gather_relu<<<(N + 15) / 16, 256, 0, stream>>>(buf0, srcs, row_start, cnt, dinv, b1, buf1, N);
    // layer 2: g2 = (z1@W2)*dinv -> buf0 ; z2 -> buf1
    k_gemm_scale<_Float16><<<(N + 63) / 64, 256, 0, stream>>>(buf1, W2, dinv, buf0, N);
    k_gather_relu<<<(N + 15) / 16, 256, 0, stream>>>(buf0, srcs, row_start, cnt, dinv, b2, buf1, N);
    // decode
    k_decode<<<(EL + 15) / 16, 256, 0, stream>>>(buf1, eli, out, EL);
}

// Round 7
// 407.584 us; speedup vs baseline: 1.1902x; 1.1879x over previous
//
#include <hip/hip_runtime.h>
#include <hip/hip_bf16.h>
#include <hip/hip_fp16.h>

// ---------------------------------------------------------------------------
// GCN link predictor, fp16 intermediate buffers (fp32 accumulate everywhere):
//   dinv[v] = rsqrt(indeg(v)+1)
//   g  = (X @ W) * dinv[row]            (fused in GEMM epilogue, stored fp16)
//   z  = relu(dinv[v]*(g[v] + sum_{s->v} g[s]) + b)   (CSR gather, fused)
//   out[e] = dot(z2[s_e], z2[d_e])      (fp32 accumulate)
// CSR built per call, fully bucket-local (no per-node global atomics):
//   R4: naive scatter = 107 MB write-allocate. R6: global-atomic histogram
//   = 50 MB sector writeback (1.6M atomics x 32B). R7: bucket counting sort
//   (bhist/bscan/bscatter) -> pairs bucket-sorted by dst>>8; then one fused
//   per-bucket kernel builds row_start/cnt/dinv AND scatters srcs via LDS
//   histogram + scan (global row_start = bstart[b] + local excl scan).
// ---------------------------------------------------------------------------

typedef _Float16 half8 __attribute__((ext_vector_type(8)));
typedef _Float16 half4 __attribute__((ext_vector_type(4)));

#define BK_SHIFT 8
#define BH_EDGES 1024   // edges per block in bucket histogram
#define BSC_EDGES 2048  // edges per block in binning scatter

__global__ __launch_bounds__(256) void k_zero(int* __restrict__ p, int n) {
    int i = blockIdx.x * 256 + threadIdx.x;
    if (i < n) p[i] = 0;
}

// ---- bucket histogram: LDS-accumulated, one global atomic per block/bucket
__global__ __launch_bounds__(256) void k_bhist(const int* __restrict__ dst,
                                               int* __restrict__ bcnt,
                                               int E, int nbk) {
    __shared__ int lcnt[1024];
    int tid = threadIdx.x;
    for (int b = tid; b < nbk; b += 256) lcnt[b] = 0;
    __syncthreads();
    int e0 = blockIdx.x * BH_EDGES;
#pragma unroll
    for (int k = 0; k < BH_EDGES / 256; ++k) {
        int e = e0 + k * 256 + tid;
        if (e < E) atomicAdd(&lcnt[dst[e] >> BK_SHIFT], 1);
    }
    __syncthreads();
    for (int b = tid; b < nbk; b += 256)
        if (lcnt[b]) atomicAdd(&bcnt[b], lcnt[b]);
}

// ---- exclusive scan of bucket counts; bstart[nbk] = E; bfill = bstart copy
__global__ __launch_bounds__(1024) void k_bscan(const int* __restrict__ bcnt,
                                                int* __restrict__ bstart,
                                                int* __restrict__ bfill,
                                                int nbk, int E) {
    __shared__ int sh[1024];
    int tid = threadIdx.x;
    int v = (tid < nbk) ? bcnt[tid] : 0;
    sh[tid] = v;
    __syncthreads();
    for (int off = 1; off < 1024; off <<= 1) {
        int t = (tid >= off) ? sh[tid - off] : 0;
        __syncthreads();
        sh[tid] += t;
        __syncthreads();
    }
    if (tid < nbk) {
        int ex = sh[tid] - v;
        bstart[tid] = ex;
        bfill[tid] = ex;
    }
    if (tid == 0) bstart[nbk] = E;
}

// ---- LDS-binned scatter of (src,dst) pairs into bucket-sorted order.
// Per block: local count -> full-block scan + bulk global claims -> local
// scatter into LDS staging -> linear copy-out (contiguous runs per bucket).
__global__ __launch_bounds__(256) void k_bscatter(const int* __restrict__ src,
                                                  const int* __restrict__ dst,
                                                  int* __restrict__ bfill,
                                                  int2* __restrict__ pairs,
                                                  int E, int nbk) {
    __shared__ int lcnt[1024];    // counts, then fill cursor (= lbase)
    __shared__ int delta[1024];   // gbase - lbase per bucket
    __shared__ int ssum[256];     // block-scan workspace
    __shared__ int2 stage[BSC_EDGES];
    int tid = threadIdx.x;
    int e0 = blockIdx.x * BSC_EDGES;
    int nloc = E - e0; if (nloc > BSC_EDGES) nloc = BSC_EDGES;

    for (int b = tid; b < nbk; b += 256) lcnt[b] = 0;
    __syncthreads();

    int d[BSC_EDGES / 256], s[BSC_EDGES / 256];
#pragma unroll
    for (int k = 0; k < BSC_EDGES / 256; ++k) {
        int e = e0 + k * 256 + tid;
        if (e < E) {
            d[k] = dst[e];
            s[k] = src[e];
            atomicAdd(&lcnt[d[k] >> BK_SHIFT], 1);
        } else d[k] = -1;
    }
    __syncthreads();

    // full-block exclusive scan over nbk buckets (each thread owns gpb)
    const int gpb = (nbk + 255) >> 8;   // <=4 for nbk<=1024
    int c[4], mysum = 0;
    for (int t = 0; t < gpb; ++t) {
        int b = tid * gpb + t;
        c[t] = (b < nbk) ? lcnt[b] : 0;
        mysum += c[t];
    }
    ssum[tid] = mysum;
    __syncthreads();
    for (int off = 1; off < 256; off <<= 1) {
        int t = (tid >= off) ? ssum[tid - off] : 0;
        __syncthreads();
        ssum[tid] += t;
        __syncthreads();
    }
    int base = ssum[tid] - mysum;  // exclusive prefix of this thread's group
    for (int t = 0; t < gpb; ++t) {
        int b = tid * gpb + t;
        if (b < nbk) {
            int g = c[t] ? atomicAdd(&bfill[b], c[t]) : 0;
            delta[b] = g - base;   // gbase - lbase
            lcnt[b] = base;        // cursor starts at lbase
            base += c[t];
        }
    }
    __syncthreads();

    // local scatter into staging (bucket-grouped within block)
#pragma unroll
    for (int k = 0; k < BSC_EDGES / 256; ++k) {
        if (d[k] >= 0) {
            int b = d[k] >> BK_SHIFT;
            int lp = atomicAdd(&lcnt[b], 1);
            int2 p; p.x = s[k]; p.y = d[k];
            stage[lp] = p;
        }
    }
    __syncthreads();

    // copy-out: consecutive j in same bucket -> consecutive global addresses
    for (int j = tid; j < nloc; j += 256) {
        int2 p = stage[j];
        pairs[delta[p.y >> BK_SHIFT] + j] = p;
    }
}

// ---- fused CSR build, one block per bucket (256 nodes, bucket-sorted pairs):
// LDS histogram by dst&255 -> LDS scan -> row_start = bstart[b] + excl
// (globally correct), write row_start/cnt/dinv, then scatter srcs through
// LDS fill cursors. Second pairs pass is L1-resident (~32 KB/block).
__global__ __launch_bounds__(256) void k_csr(const int2* __restrict__ pairs,
                                             const int* __restrict__ bstart,
                                             int* __restrict__ row_start,
                                             int* __restrict__ cnt,
                                             float* __restrict__ dinv,
                                             int* __restrict__ srcs, int n) {
    __shared__ int lcnt[256];
    __shared__ int lpos[256];
    int tid = threadIdx.x;
    int b = blockIdx.x;
    lcnt[tid] = 0;
    __syncthreads();
    int beg = bstart[b], end = bstart[b + 1];
    for (int i = beg + tid; i < end; i += 256)
        atomicAdd(&lcnt[pairs[i].y & 255], 1);
    __syncthreads();
    int c = lcnt[tid];
    lpos[tid] = c;
    __syncthreads();
    for (int off = 1; off < 256; off <<= 1) {
        int t = (tid >= off) ? lpos[tid - off] : 0;
        __syncthreads();
        lpos[tid] += t;
        __syncthreads();
    }
    int rs = beg + lpos[tid] - c;   // global row start
    int v = (b << BK_SHIFT) + tid;
    if (v < n) {
        row_start[v] = rs;
        cnt[v] = c;
        dinv[v] = rsqrtf((float)c + 1.0f);
    }
    __syncthreads();
    lpos[tid] = rs;                 // reuse as fill cursor
    __syncthreads();
    for (int i = beg + tid; i < end; i += 256) {
        int2 p = pairs[i];
        int loc = atomicAdd(&lpos[p.y & 255], 1);
        srcs[loc] = p.x;
    }
}

// ---------------------------------------------------------------------------
// GEMM: G[r][c] = dinv[r] * sum_k A[r][k]*W[k][c]    (N x 128) @ (128 x 128)
// A is fp32 (layer 1: x) or fp16 (layer 2: z1). Output G is fp16.
// ---------------------------------------------------------------------------
template <typename AT>
__global__ __launch_bounds__(256, 4) void k_gemm_scale(const AT* __restrict__ X,
                                                       const float* __restrict__ W,
                                                       const float* __restrict__ dinv,
                                                       _Float16* __restrict__ G, int n) {
    __shared__ float Wl[32 * 128];
    const int tid = threadIdx.x;
    const int colgrp = tid & 15;
    const int rowgrp = tid >> 4;
    const int r0 = blockIdx.x * 64 + rowgrp * 4;
    const int c0 = colgrp * 4;

    const AT* Xr[4];
#pragma unroll
    for (int i = 0; i < 4; ++i) {
        int r = r0 + i;
        if (r >= n) r = n - 1;
        Xr[i] = X + (size_t)r * 128;
    }

    float acc[4][8] = {};

    auto loadA = [](const AT* p) -> float4 {
        if constexpr (sizeof(AT) == 4) {
            return *(const float4*)p;
        } else {
            half4 h = *(const half4*)p;
            float4 f;
            f.x = (float)h[0]; f.y = (float)h[1];
            f.z = (float)h[2]; f.w = (float)h[3];
            return f;
        }
    };

    for (int kc = 0; kc < 128; kc += 32) {
        {
            const float4* W4 = (const float4*)(W + (size_t)kc * 128);
            float4* Wl4 = (float4*)Wl;
#pragma unroll
            for (int it = 0; it < 4; ++it)
                Wl4[it * 256 + tid] = W4[it * 256 + tid];
        }
        __syncthreads();

        float4 a_cur[4], a_nxt[4];
#pragma unroll
        for (int i = 0; i < 4; ++i) a_cur[i] = loadA(Xr[i] + kc);

#pragma unroll 1
        for (int k4 = 0; k4 < 28; k4 += 4) {
#pragma unroll
            for (int i = 0; i < 4; ++i) a_nxt[i] = loadA(Xr[i] + kc + k4 + 4);
#pragma unroll
            for (int kk = 0; kk < 4; ++kk) {
                float4 b0 = *(const float4*)(Wl + (k4 + kk) * 128 + c0);
                float4 b1 = *(const float4*)(Wl + (k4 + kk) * 128 + c0 + 64);
#pragma unroll
                for (int i = 0; i < 4; ++i) {
                    float av = (kk == 0) ? a_cur[i].x : (kk == 1) ? a_cur[i].y
                             : (kk == 2) ? a_cur[i].z : a_cur[i].w;
                    acc[i][0] += av * b0.x; acc[i][1] += av * b0.y;
                    acc[i][2] += av * b0.z; acc[i][3] += av * b0.w;
                    acc[i][4] += av * b1.x; acc[i][5] += av * b1.y;
                    acc[i][6] += av * b1.z; acc[i][7] += av * b1.w;
                }
            }
#pragma unroll
            for (int i = 0; i < 4; ++i) a_cur[i] = a_nxt[i];
        }
#pragma unroll
        for (int kk = 0; kk < 4; ++kk) {
            float4 b0 = *(const float4*)(Wl + (28 + kk) * 128 + c0);
            float4 b1 = *(const float4*)(Wl + (28 + kk) * 128 + c0 + 64);
#pragma unroll
            for (int i = 0; i < 4; ++i) {
                float av = (kk == 0) ? a_cur[i].x : (kk == 1) ? a_cur[i].y
                         : (kk == 2) ? a_cur[i].z : a_cur[i].w;
                acc[i][0] += av * b0.x; acc[i][1] += av * b0.y;
                acc[i][2] += av * b0.z; acc[i][3] += av * b0.w;
                acc[i][4] += av * b1.x; acc[i][5] += av * b1.y;
                acc[i][6] += av * b1.z; acc[i][7] += av * b1.w;
            }
        }
        __syncthreads();
    }

#pragma unroll
    for (int i = 0; i < 4; ++i) {
        int r = r0 + i;
        if (r < n) {
            float dv = dinv[r];
            half4 o0, o1;
#pragma unroll
            for (int j = 0; j < 4; ++j) {
                o0[j] = (_Float16)(acc[i][j] * dv);
                o1[j] = (_Float16)(acc[i][4 + j] * dv);
            }
            *(half4*)(G + (size_t)r * 128 + c0) = o0;
            *(half4*)(G + (size_t)r * 128 + c0 + 64) = o1;
        }
    }
}

// ---------------------------------------------------------------------------
// Gather-aggregate + bias + relu. 16 lanes per node (half8 over 128 dims),
// 16 nodes per 256-thread block. acc init = g[v] (self loop), fp32 accum.
// ---------------------------------------------------------------------------
__global__ __launch_bounds__(256) void k_gather_relu(const _Float16* __restrict__ G,
                                                     const int* __restrict__ srcs,
                                                     const int* __restrict__ row_start,
                                                     const int* __restrict__ cnt,
                                                     const float* __restrict__ dinv,
                                                     const float* __restrict__ bias,
                                                     _Float16* __restrict__ Z, int n) {
    int v = blockIdx.x * 16 + (threadIdx.x >> 4);
    int lane = threadIdx.x & 15;
    if (v >= n) return;
    const half8* G8 = (const half8*)G;

    half8 self = G8[(size_t)v * 16 + lane];
    float acc[8], acc2[8];
#pragma unroll
    for (int j = 0; j < 8; ++j) { acc[j] = (float)self[j]; acc2[j] = 0.f; }

    int beg = row_start[v], deg = cnt[v];
    int e = 0;
    for (; e + 3 < deg; e += 4) {
        int s0 = srcs[beg + e];
        int s1 = srcs[beg + e + 1];
        int s2 = srcs[beg + e + 2];
        int s3 = srcs[beg + e + 3];
        half8 t0 = G8[(size_t)s0 * 16 + lane];
        half8 t1 = G8[(size_t)s1 * 16 + lane];
        half8 t2 = G8[(size_t)s2 * 16 + lane];
        half8 t3 = G8[(size_t)s3 * 16 + lane];
#pragma unroll
        for (int j = 0; j < 8; ++j) {
            acc[j]  += (float)t0[j] + (float)t1[j];
            acc2[j] += (float)t2[j] + (float)t3[j];
        }
    }
    for (; e < deg; ++e) {
        int s0 = srcs[beg + e];
        half8 t0 = G8[(size_t)s0 * 16 + lane];
#pragma unroll
        for (int j = 0; j < 8; ++j) acc[j] += (float)t0[j];
    }

    float dv = dinv[v];
    const float4* b4 = (const float4*)bias;
    float4 bb0 = b4[lane * 2], bb1 = b4[lane * 2 + 1];
    float bf[8] = {bb0.x, bb0.y, bb0.z, bb0.w, bb1.x, bb1.y, bb1.z, bb1.w};
    half8 zo;
#pragma unroll
    for (int j = 0; j < 8; ++j) {
        float z = dv * (acc[j] + acc2[j]) + bf[j];
        zo[j] = (_Float16)fmaxf(z, 0.f);
    }
    ((half8*)Z)[(size_t)v * 16 + lane] = zo;
}

// ---------------------------------------------------------------------------
// Decode: out[e] = dot(Z[s_e], Z[d_e]) over 128 dims (fp16 rows, fp32 accum).
// ---------------------------------------------------------------------------
__global__ __launch_bounds__(256) void k_decode(const _Float16* __restrict__ Z,
                                                const int* __restrict__ eli,
                                                float* __restrict__ out, int el) {
    int sub = threadIdx.x >> 4, lane = threadIdx.x & 15;
    int e = blockIdx.x * 16 + sub;
    if (e >= el) return;
    int s = eli[e], d = eli[el + e];
    const half8* Z8 = (const half8*)Z;
    half8 a = Z8[(size_t)s * 16 + lane];
    half8 b = Z8[(size_t)d * 16 + lane];
    float dot = 0.f;
#pragma unroll
    for (int j = 0; j < 8; ++j) dot += (float)a[j] * (float)b[j];
#pragma unroll
    for (int off = 8; off; off >>= 1) dot += __shfl_down(dot, off, 16);
    if (lane == 0) out[e] = dot;
}

extern "C" void kernel_launch(void* const* d_in, const int* in_sizes, int n_in,
                              void* d_out, int out_size, void* d_ws, size_t ws_size,
                              hipStream_t stream) {
    const float* x  = (const float*)d_in[0];
    const int*  ei  = (const int*)d_in[1];
    const int*  eli = (const int*)d_in[2];
    const float* W1 = (const float*)d_in[3];
    const float* b1 = (const float*)d_in[4];
    const float* W2 = (const float*)d_in[5];
    const float* b2 = (const float*)d_in[6];
    float* out = (float*)d_out;

    const int N  = in_sizes[0] / 128;
    const int E  = in_sizes[1] / 2;
    const int EL = in_sizes[2] / 2;
    const int* src = ei;
    const int* dst = ei + E;
    const int NBK = (N + 255) >> BK_SHIFT;   // 391 for N=100000 (<=1024)

    char* ws = (char*)d_ws;
    size_t off = 0;
    auto alloc = [&](size_t bytes) -> void* {
        void* p = ws + off;
        off += bytes;
        off = (off + 255) & ~(size_t)255;
        return p;
    };
    int*       cnt       = (int*)alloc((size_t)N * 4);
    int*       bcnt      = (int*)alloc(4096);
    int*       row_start = (int*)alloc((size_t)N * 4);
    float*     dinv      = (float*)alloc((size_t)N * 4);
    int*       bstart    = (int*)alloc(4100);
    int*       bfill     = (int*)alloc(4096);
    int*       srcs      = (int*)alloc((size_t)E * 4);
    int2*      pairs     = (int2*)alloc((size_t)E * 8);
    _Float16*  buf0      = (_Float16*)alloc((size_t)N * 128 * 2);  // G (pre-agg)
    _Float16*  buf1      = (_Float16*)alloc((size_t)N * 128 * 2);  // Z (post-agg)

    // CSR build: bucket counting sort, no per-node global atomics
    k_zero<<<4, 256, 0, stream>>>(bcnt, 1024);
    k_bhist<<<(E + BH_EDGES - 1) / BH_EDGES, 256, 0, stream>>>(dst, bcnt, E, NBK);
    k_bscan<<<1, 1024, 0, stream>>>(bcnt, bstart, bfill, NBK, E);
    k_bscatter<<<(E + BSC_EDGES - 1) / BSC_EDGES, 256, 0, stream>>>(src, dst, bfill, pairs, E, NBK);
    k_csr<<<NBK, 256, 0, stream>>>(pairs, bstart, row_start, cnt, dinv, srcs, N);

    // layer 1: g1 = (x@W1)*dinv -> buf0 (fp16) ; z1 -> buf1 (fp16)
    k_gemm_scale<float><<<(N + 63) / 64, 256, 0, stream>>>(x, W1, dinv, buf0, N);
    k_gather_relu<<<(N + 15) / 16, 256, 0, stream>>>(buf0, srcs, row_start, cnt, dinv, b1, buf1, N);
    // layer 2: g2 = (z1@W2)*dinv -> buf0 ; z2 -> buf1
    k_gemm_scale<_Float16><<<(N + 63) / 64, 256, 0, stream>>>(buf1, W2, dinv, buf0, N);
    k_gather_relu<<<(N + 15) / 16, 256, 0, stream>>>(buf0, srcs, row_start, cnt, dinv, b2, buf1, N);
    // decode
    k_decode<<<(EL + 15) / 16, 256, 0, stream>>>(buf1, eli, out, EL);
}

// Round 8
// 383.975 us; speedup vs baseline: 1.2634x; 1.0615x over previous
//
#include <hip/hip_runtime.h>
#include <hip/hip_bf16.h>
#include <hip/hip_fp16.h>

// ---------------------------------------------------------------------------
// GCN link predictor, fp16 intermediates + MFMA GEMM (fp32 accumulate):
//   dinv[v] = rsqrt(indeg(v)+1)
//   g  = (X @ W) * dinv[row]            (MFMA GEMM epilogue, stored fp16)
//   z  = relu(dinv[v]*(g[v] + sum_{s->v} g[s]) + b)   (CSR gather, fused)
//   out[e] = dot(z2[s_e], z2[d_e])      (fp32 accumulate)
// CSR built per call, fully bucket-local (no per-node global atomics).
// R7 lesson: VALU GEMM = 64 µs/layer with matrix pipe idle (VALUBusy 52%,
// MfmaUtil 0). R8: mfma_f32_16x16x32_f16, W pre-transposed to fp16 WT[c][k];
// A-frag A[m=lane&15][k=quad*8+j] (16B/lane), B-frag likewise from WT rows,
// C/D col=lane&15,row=quad*4+reg (m89-verified). No LDS, no K-loop barriers.
// ---------------------------------------------------------------------------

typedef _Float16 half8 __attribute__((ext_vector_type(8)));
typedef _Float16 half4 __attribute__((ext_vector_type(4)));
typedef float floatx4 __attribute__((ext_vector_type(4)));

#define BK_SHIFT 8
#define BH_EDGES 1024   // edges per block in bucket histogram
#define BSC_EDGES 2048  // edges per block in binning scatter

__global__ __launch_bounds__(256) void k_zero(int* __restrict__ p, int n) {
    int i = blockIdx.x * 256 + threadIdx.x;
    if (i < n) p[i] = 0;
}

// ---- transpose + fp16-cast the two weight matrices: WT[c][k] = W[k][c]
__global__ __launch_bounds__(128) void k_wprep(const float* __restrict__ W1,
                                               const float* __restrict__ W2,
                                               _Float16* __restrict__ WT1,
                                               _Float16* __restrict__ WT2) {
    int b = blockIdx.x;               // 0..255
    const float* W = (b < 128) ? W1 : W2;
    _Float16* WT = (b < 128) ? WT1 : WT2;
    int k = b & 127;
    int c = threadIdx.x;
    WT[c * 128 + k] = (_Float16)W[k * 128 + c];
}

// ---- bucket histogram: LDS-accumulated, one global atomic per block/bucket
__global__ __launch_bounds__(256) void k_bhist(const int* __restrict__ dst,
                                               int* __restrict__ bcnt,
                                               int E, int nbk) {
    __shared__ int lcnt[1024];
    int tid = threadIdx.x;
    for (int b = tid; b < nbk; b += 256) lcnt[b] = 0;
    __syncthreads();
    int e0 = blockIdx.x * BH_EDGES;
#pragma unroll
    for (int k = 0; k < BH_EDGES / 256; ++k) {
        int e = e0 + k * 256 + tid;
        if (e < E) atomicAdd(&lcnt[dst[e] >> BK_SHIFT], 1);
    }
    __syncthreads();
    for (int b = tid; b < nbk; b += 256)
        if (lcnt[b]) atomicAdd(&bcnt[b], lcnt[b]);
}

// ---- exclusive scan of bucket counts; bstart[nbk] = E; bfill = bstart copy
__global__ __launch_bounds__(1024) void k_bscan(const int* __restrict__ bcnt,
                                                int* __restrict__ bstart,
                                                int* __restrict__ bfill,
                                                int nbk, int E) {
    __shared__ int sh[1024];
    int tid = threadIdx.x;
    int v = (tid < nbk) ? bcnt[tid] : 0;
    sh[tid] = v;
    __syncthreads();
    for (int off = 1; off < 1024; off <<= 1) {
        int t = (tid >= off) ? sh[tid - off] : 0;
        __syncthreads();
        sh[tid] += t;
        __syncthreads();
    }
    if (tid < nbk) {
        int ex = sh[tid] - v;
        bstart[tid] = ex;
        bfill[tid] = ex;
    }
    if (tid == 0) bstart[nbk] = E;
}

// ---- LDS-binned scatter of (src,dst) pairs into bucket-sorted order.
__global__ __launch_bounds__(256) void k_bscatter(const int* __restrict__ src,
                                                  const int* __restrict__ dst,
                                                  int* __restrict__ bfill,
                                                  int2* __restrict__ pairs,
                                                  int E, int nbk) {
    __shared__ int lcnt[1024];    // counts, then fill cursor (= lbase)
    __shared__ int delta[1024];   // gbase - lbase per bucket
    __shared__ int ssum[256];     // block-scan workspace
    __shared__ int2 stage[BSC_EDGES];
    int tid = threadIdx.x;
    int e0 = blockIdx.x * BSC_EDGES;
    int nloc = E - e0; if (nloc > BSC_EDGES) nloc = BSC_EDGES;

    for (int b = tid; b < nbk; b += 256) lcnt[b] = 0;
    __syncthreads();

    int d[BSC_EDGES / 256], s[BSC_EDGES / 256];
#pragma unroll
    for (int k = 0; k < BSC_EDGES / 256; ++k) {
        int e = e0 + k * 256 + tid;
        if (e < E) {
            d[k] = dst[e];
            s[k] = src[e];
            atomicAdd(&lcnt[d[k] >> BK_SHIFT], 1);
        } else d[k] = -1;
    }
    __syncthreads();

    const int gpb = (nbk + 255) >> 8;   // <=4 for nbk<=1024
    int c[4], mysum = 0;
    for (int t = 0; t < gpb; ++t) {
        int b = tid * gpb + t;
        c[t] = (b < nbk) ? lcnt[b] : 0;
        mysum += c[t];
    }
    ssum[tid] = mysum;
    __syncthreads();
    for (int off = 1; off < 256; off <<= 1) {
        int t = (tid >= off) ? ssum[tid - off] : 0;
        __syncthreads();
        ssum[tid] += t;
        __syncthreads();
    }
    int base = ssum[tid] - mysum;
    for (int t = 0; t < gpb; ++t) {
        int b = tid * gpb + t;
        if (b < nbk) {
            int g = c[t] ? atomicAdd(&bfill[b], c[t]) : 0;
            delta[b] = g - base;   // gbase - lbase
            lcnt[b] = base;        // cursor starts at lbase
            base += c[t];
        }
    }
    __syncthreads();

#pragma unroll
    for (int k = 0; k < BSC_EDGES / 256; ++k) {
        if (d[k] >= 0) {
            int b = d[k] >> BK_SHIFT;
            int lp = atomicAdd(&lcnt[b], 1);
            int2 p; p.x = s[k]; p.y = d[k];
            stage[lp] = p;
        }
    }
    __syncthreads();

    for (int j = tid; j < nloc; j += 256) {
        int2 p = stage[j];
        pairs[delta[p.y >> BK_SHIFT] + j] = p;
    }
}

// ---- fused CSR build, one block per bucket (256 nodes, bucket-sorted pairs)
__global__ __launch_bounds__(256) void k_csr(const int2* __restrict__ pairs,
                                             const int* __restrict__ bstart,
                                             int* __restrict__ row_start,
                                             int* __restrict__ cnt,
                                             float* __restrict__ dinv,
                                             int* __restrict__ srcs, int n) {
    __shared__ int lcnt[256];
    __shared__ int lpos[256];
    int tid = threadIdx.x;
    int b = blockIdx.x;
    lcnt[tid] = 0;
    __syncthreads();
    int beg = bstart[b], end = bstart[b + 1];
    for (int i = beg + tid; i < end; i += 256)
        atomicAdd(&lcnt[pairs[i].y & 255], 1);
    __syncthreads();
    int c = lcnt[tid];
    lpos[tid] = c;
    __syncthreads();
    for (int off = 1; off < 256; off <<= 1) {
        int t = (tid >= off) ? lpos[tid - off] : 0;
        __syncthreads();
        lpos[tid] += t;
        __syncthreads();
    }
    int rs = beg + lpos[tid] - c;   // global row start
    int v = (b << BK_SHIFT) + tid;
    if (v < n) {
        row_start[v] = rs;
        cnt[v] = c;
        dinv[v] = rsqrtf((float)c + 1.0f);
    }
    __syncthreads();
    lpos[tid] = rs;                 // reuse as fill cursor
    __syncthreads();
    for (int i = beg + tid; i < end; i += 256) {
        int2 p = pairs[i];
        int loc = atomicAdd(&lpos[p.y & 255], 1);
        srcs[loc] = p.x;
    }
}

// ---------------------------------------------------------------------------
// MFMA GEMM: G[r][c] = dinv[r] * sum_k A[r][k]*W[k][c]   (N x 128)@(128 x 128)
// A fp32 (layer 1) or fp16 (layer 2); WT = fp16 W^T [c][k]; G fp16.
// 4 waves/block, wave = 16 rows x 128 cols: 8 acc tiles, K-loop of 4 x K=32.
// A-frag: lane loads 16B at X[m0+(lane&15)][kc+quad*8] (fp32 path: 32B+cvt).
// B-frag: lane loads 16B at WT[t*16+(lane&15)][kc+quad*8] (L1-resident 32KB).
// D: col=lane&15, row=quad*4+reg.  No LDS, no barriers.
// ---------------------------------------------------------------------------
template <typename AT>
__global__ __launch_bounds__(256) void k_gemm_mfma(const AT* __restrict__ X,
                                                   const _Float16* __restrict__ WT,
                                                   const float* __restrict__ dinv,
                                                   _Float16* __restrict__ G, int n) {
    int tid = threadIdx.x;
    int wave = tid >> 6, lane = tid & 63;
    int q = lane >> 4, ln = lane & 15;
    int m0 = blockIdx.x * 64 + wave * 16;
    int mA = m0 + ln; if (mA >= n) mA = n - 1;   // clamp: harmless dup load
    const AT* xrow = X + (size_t)mA * 128;

    floatx4 acc[8];
#pragma unroll
    for (int t = 0; t < 8; ++t) acc[t] = (floatx4){0.f, 0.f, 0.f, 0.f};

#pragma unroll
    for (int kc = 0; kc < 128; kc += 32) {
        half8 a;
        if constexpr (sizeof(AT) == 4) {
            const float4* p = (const float4*)(xrow + kc + q * 8);
            float4 f0 = p[0], f1 = p[1];
            a[0] = (_Float16)f0.x; a[1] = (_Float16)f0.y;
            a[2] = (_Float16)f0.z; a[3] = (_Float16)f0.w;
            a[4] = (_Float16)f1.x; a[5] = (_Float16)f1.y;
            a[6] = (_Float16)f1.z; a[7] = (_Float16)f1.w;
        } else {
            a = *(const half8*)(xrow + kc + q * 8);
        }
#pragma unroll
        for (int t = 0; t < 8; ++t) {
            half8 b = *(const half8*)(WT + (size_t)(t * 16 + ln) * 128 + kc + q * 8);
            acc[t] = __builtin_amdgcn_mfma_f32_16x16x32_f16(a, b, acc[t], 0, 0, 0);
        }
    }

#pragma unroll
    for (int r = 0; r < 4; ++r) {
        int row = m0 + q * 4 + r;
        if (row < n) {
            float dv = dinv[row];
            _Float16* grow = G + (size_t)row * 128 + ln;
#pragma unroll
            for (int t = 0; t < 8; ++t)
                grow[t * 16] = (_Float16)(acc[t][r] * dv);
        }
    }
}

// ---------------------------------------------------------------------------
// Gather-aggregate + bias + relu. 16 lanes per node (half8 over 128 dims),
// 16 nodes per 256-thread block. acc init = g[v] (self loop), fp32 accum.
// ---------------------------------------------------------------------------
__global__ __launch_bounds__(256) void k_gather_relu(const _Float16* __restrict__ G,
                                                     const int* __restrict__ srcs,
                                                     const int* __restrict__ row_start,
                                                     const int* __restrict__ cnt,
                                                     const float* __restrict__ dinv,
                                                     const float* __restrict__ bias,
                                                     _Float16* __restrict__ Z, int n) {
    int v = blockIdx.x * 16 + (threadIdx.x >> 4);
    int lane = threadIdx.x & 15;
    if (v >= n) return;
    const half8* G8 = (const half8*)G;

    half8 self = G8[(size_t)v * 16 + lane];
    float acc[8], acc2[8];
#pragma unroll
    for (int j = 0; j < 8; ++j) { acc[j] = (float)self[j]; acc2[j] = 0.f; }

    int beg = row_start[v], deg = cnt[v];
    int e = 0;
    for (; e + 3 < deg; e += 4) {
        int s0 = srcs[beg + e];
        int s1 = srcs[beg + e + 1];
        int s2 = srcs[beg + e + 2];
        int s3 = srcs[beg + e + 3];
        half8 t0 = G8[(size_t)s0 * 16 + lane];
        half8 t1 = G8[(size_t)s1 * 16 + lane];
        half8 t2 = G8[(size_t)s2 * 16 + lane];
        half8 t3 = G8[(size_t)s3 * 16 + lane];
#pragma unroll
        for (int j = 0; j < 8; ++j) {
            acc[j]  += (float)t0[j] + (float)t1[j];
            acc2[j] += (float)t2[j] + (float)t3[j];
        }
    }
    for (; e < deg; ++e) {
        int s0 = srcs[beg + e];
        half8 t0 = G8[(size_t)s0 * 16 + lane];
#pragma unroll
        for (int j = 0; j < 8; ++j) acc[j] += (float)t0[j];
    }

    float dv = dinv[v];
    const float4* b4 = (const float4*)bias;
    float4 bb0 = b4[lane * 2], bb1 = b4[lane * 2 + 1];
    float bf[8] = {bb0.x, bb0.y, bb0.z, bb0.w, bb1.x, bb1.y, bb1.z, bb1.w};
    half8 zo;
#pragma unroll
    for (int j = 0; j < 8; ++j) {
        float z = dv * (acc[j] + acc2[j]) + bf[j];
        zo[j] = (_Float16)fmaxf(z, 0.f);
    }
    ((half8*)Z)[(size_t)v * 16 + lane] = zo;
}

// ---------------------------------------------------------------------------
// Decode: out[e] = dot(Z[s_e], Z[d_e]) over 128 dims (fp16 rows, fp32 accum).
// ---------------------------------------------------------------------------
__global__ __launch_bounds__(256) void k_decode(const _Float16* __restrict__ Z,
                                                const int* __restrict__ eli,
                                                float* __restrict__ out, int el) {
    int sub = threadIdx.x >> 4, lane = threadIdx.x & 15;
    int e = blockIdx.x * 16 + sub;
    if (e >= el) return;
    int s = eli[e], d = eli[el + e];
    const half8* Z8 = (const half8*)Z;
    half8 a = Z8[(size_t)s * 16 + lane];
    half8 b = Z8[(size_t)d * 16 + lane];
    float dot = 0.f;
#pragma unroll
    for (int j = 0; j < 8; ++j) dot += (float)a[j] * (float)b[j];
#pragma unroll
    for (int off = 8; off; off >>= 1) dot += __shfl_down(dot, off, 16);
    if (lane == 0) out[e] = dot;
}

extern "C" void kernel_launch(void* const* d_in, const int* in_sizes, int n_in,
                              void* d_out, int out_size, void* d_ws, size_t ws_size,
                              hipStream_t stream) {
    const float* x  = (const float*)d_in[0];
    const int*  ei  = (const int*)d_in[1];
    const int*  eli = (const int*)d_in[2];
    const float* W1 = (const float*)d_in[3];
    const float* b1 = (const float*)d_in[4];
    const float* W2 = (const float*)d_in[5];
    const float* b2 = (const float*)d_in[6];
    float* out = (float*)d_out;

    const int N  = in_sizes[0] / 128;
    const int E  = in_sizes[1] / 2;
    const int EL = in_sizes[2] / 2;
    const int* src = ei;
    const int* dst = ei + E;
    const int NBK = (N + 255) >> BK_SHIFT;   // 391 for N=100000 (<=1024)

    char* ws = (char*)d_ws;
    size_t off = 0;
    auto alloc = [&](size_t bytes) -> void* {
        void* p = ws + off;
        off += bytes;
        off = (off + 255) & ~(size_t)255;
        return p;
    };
    int*       cnt       = (int*)alloc((size_t)N * 4);
    int*       bcnt      = (int*)alloc(4096);
    int*       row_start = (int*)alloc((size_t)N * 4);
    float*     dinv      = (float*)alloc((size_t)N * 4);
    int*       bstart    = (int*)alloc(4100);
    int*       bfill     = (int*)alloc(4096);
    _Float16*  WT1       = (_Float16*)alloc(128 * 128 * 2);
    _Float16*  WT2       = (_Float16*)alloc(128 * 128 * 2);
    int*       srcs      = (int*)alloc((size_t)E * 4);
    int2*      pairs     = (int2*)alloc((size_t)E * 8);
    _Float16*  buf0      = (_Float16*)alloc((size_t)N * 128 * 2);  // G (pre-agg)
    _Float16*  buf1      = (_Float16*)alloc((size_t)N * 128 * 2);  // Z (post-agg)

    // weight prep (independent of CSR chain)
    k_wprep<<<256, 128, 0, stream>>>(W1, W2, WT1, WT2);

    // CSR build: bucket counting sort, no per-node global atomics
    k_zero<<<4, 256, 0, stream>>>(bcnt, 1024);
    k_bhist<<<(E + BH_EDGES - 1) / BH_EDGES, 256, 0, stream>>>(dst, bcnt, E, NBK);
    k_bscan<<<1, 1024, 0, stream>>>(bcnt, bstart, bfill, NBK, E);
    k_bscatter<<<(E + BSC_EDGES - 1) / BSC_EDGES, 256, 0, stream>>>(src, dst, bfill, pairs, E, NBK);
    k_csr<<<NBK, 256, 0, stream>>>(pairs, bstart, row_start, cnt, dinv, srcs, N);

    // layer 1: g1 = (x@W1)*dinv -> buf0 (fp16) ; z1 -> buf1 (fp16)
    k_gemm_mfma<float><<<(N + 63) / 64, 256, 0, stream>>>(x, WT1, dinv, buf0, N);
    k_gather_relu<<<(N + 15) / 16, 256, 0, stream>>>(buf0, srcs, row_start, cnt, dinv, b1, buf1, N);
    // layer 2: g2 = (z1@W2)*dinv -> buf0 ; z2 -> buf1
    k_gemm_mfma<_Float16><<<(N + 63) / 64, 256, 0, stream>>>(buf1, WT2, dinv, buf0, N);
    k_gather_relu<<<(N + 15) / 16, 256, 0, stream>>>(buf0, srcs, row_start, cnt, dinv, b2, buf1, N);
    // decode
    k_decode<<<(EL + 15) / 16, 256, 0, stream>>>(buf1, eli, out, EL);
}

// Round 9
// 331.590 us; speedup vs baseline: 1.4630x; 1.1580x over previous
//
#include <hip/hip_runtime.h>
#include <hip/hip_bf16.h>
#include <hip/hip_fp16.h>

// ---------------------------------------------------------------------------
// GCN link predictor, fp16 intermediates + MFMA GEMMs (fp32 accumulate):
//   g1 = (X @ W1) * dinv[row]                    (MFMA GEMM, stored fp16)
//   z1 = relu(dinv*(g1[v] + sum g1[s]) + b1)     (gather; z1 stays in LDS)
//   g2 = (z1 @ W2) * dinv[row]                   (MFMA fused in gather1 epi)
//   z2 = relu(dinv*(g2[v] + sum g2[s]) + b2)     (gather)
//   out[e] = dot(z2[s], z2[d])
// CSR via slab bucket sort (bucket = dst>>8, slab CAP=5120 >> 15 sigma of
// Binomial bucket counts -> no count/scan pre-pass). R4/R6 lessons: avoid
// per-node global atomics & write-allocate. R8 lesson: random 256B gather
// service rate ~3.6 TB/s is the floor; attack the tail instead.
// ---------------------------------------------------------------------------

typedef _Float16 half8 __attribute__((ext_vector_type(8)));
typedef float floatx4 __attribute__((ext_vector_type(4)));

#define BK_SHIFT 8
#define BSC_EDGES 2048  // edges per block in binning scatter
#define SLAB_CAP 5120   // per-bucket slab capacity (mean 4092, sd 64)

__global__ __launch_bounds__(256) void k_zero(int* __restrict__ p, int n) {
    int i = blockIdx.x * 256 + threadIdx.x;
    if (i < n) p[i] = 0;
}

// ---- transpose + fp16-cast the two weight matrices: WT[c][k] = W[k][c]
__global__ __launch_bounds__(128) void k_wprep(const float* __restrict__ W1,
                                               const float* __restrict__ W2,
                                               _Float16* __restrict__ WT1,
                                               _Float16* __restrict__ WT2) {
    int b = blockIdx.x;               // 0..255
    const float* W = (b < 128) ? W1 : W2;
    _Float16* WT = (b < 128) ? WT1 : WT2;
    int k = b & 127;
    int c = threadIdx.x;
    WT[c * 128 + k] = (_Float16)W[k * 128 + c];
}

// ---- LDS-binned scatter of (src,dst) pairs into per-bucket slabs.
// Per block: local count -> block scan + bulk slab claims -> local scatter
// into LDS staging -> linear copy-out (contiguous runs per bucket).
__global__ __launch_bounds__(256) void k_bscatter(const int* __restrict__ src,
                                                  const int* __restrict__ dst,
                                                  int* __restrict__ bfill,
                                                  int2* __restrict__ pairs,
                                                  int E, int nbk) {
    __shared__ int lcnt[1024];    // counts, then fill cursor (= lbase)
    __shared__ int delta[1024];   // slab_dest - lbase per bucket
    __shared__ int ssum[256];     // block-scan workspace
    __shared__ int2 stage[BSC_EDGES];
    int tid = threadIdx.x;
    int e0 = blockIdx.x * BSC_EDGES;
    int nloc = E - e0; if (nloc > BSC_EDGES) nloc = BSC_EDGES;

    for (int b = tid; b < nbk; b += 256) lcnt[b] = 0;
    __syncthreads();

    int d[BSC_EDGES / 256], s[BSC_EDGES / 256];
#pragma unroll
    for (int k = 0; k < BSC_EDGES / 256; ++k) {
        int e = e0 + k * 256 + tid;
        if (e < E) {
            d[k] = dst[e];
            s[k] = src[e];
            atomicAdd(&lcnt[d[k] >> BK_SHIFT], 1);
        } else d[k] = -1;
    }
    __syncthreads();

    const int gpb = (nbk + 255) >> 8;   // <=4 for nbk<=1024
    int c[4], mysum = 0;
    for (int t = 0; t < gpb; ++t) {
        int b = tid * gpb + t;
        c[t] = (b < nbk) ? lcnt[b] : 0;
        mysum += c[t];
    }
    ssum[tid] = mysum;
    __syncthreads();
    for (int off = 1; off < 256; off <<= 1) {
        int t = (tid >= off) ? ssum[tid - off] : 0;
        __syncthreads();
        ssum[tid] += t;
        __syncthreads();
    }
    int base = ssum[tid] - mysum;
    for (int t = 0; t < gpb; ++t) {
        int b = tid * gpb + t;
        if (b < nbk) {
            int g = c[t] ? atomicAdd(&bfill[b], c[t]) : 0;
            delta[b] = b * SLAB_CAP + g - base;   // slab dest - lbase
            lcnt[b] = base;                        // cursor starts at lbase
            base += c[t];
        }
    }
    __syncthreads();

#pragma unroll
    for (int k = 0; k < BSC_EDGES / 256; ++k) {
        if (d[k] >= 0) {
            int b = d[k] >> BK_SHIFT;
            int lp = atomicAdd(&lcnt[b], 1);
            int2 p; p.x = s[k]; p.y = d[k];
            stage[lp] = p;
        }
    }
    __syncthreads();

    for (int j = tid; j < nloc; j += 256) {
        int2 p = stage[j];
        pairs[delta[p.y >> BK_SHIFT] + j] = p;
    }
}

// ---- fused CSR build, one block per bucket slab (256 nodes):
// LDS histogram by dst&255 -> LDS scan -> row_start = slab_base + excl,
// write row_start/cnt/dinv, then scatter srcs through LDS fill cursors.
__global__ __launch_bounds__(256) void k_csr(const int2* __restrict__ pairs,
                                             const int* __restrict__ bfill,
                                             int* __restrict__ row_start,
                                             int* __restrict__ cnt,
                                             float* __restrict__ dinv,
                                             int* __restrict__ srcs, int n) {
    __shared__ int lcnt[256];
    __shared__ int lpos[256];
    int tid = threadIdx.x;
    int b = blockIdx.x;
    lcnt[tid] = 0;
    __syncthreads();
    int beg = b * SLAB_CAP, end = beg + bfill[b];
    for (int i = beg + tid; i < end; i += 256)
        atomicAdd(&lcnt[pairs[i].y & 255], 1);
    __syncthreads();
    int c = lcnt[tid];
    lpos[tid] = c;
    __syncthreads();
    for (int off = 1; off < 256; off <<= 1) {
        int t = (tid >= off) ? lpos[tid - off] : 0;
        __syncthreads();
        lpos[tid] += t;
        __syncthreads();
    }
    int rs = beg + lpos[tid] - c;   // row start (slab-relative, gaps ok)
    int v = (b << BK_SHIFT) + tid;
    if (v < n) {
        row_start[v] = rs;
        cnt[v] = c;
        dinv[v] = rsqrtf((float)c + 1.0f);
    }
    __syncthreads();
    lpos[tid] = rs;                 // reuse as fill cursor
    __syncthreads();
    for (int i = beg + tid; i < end; i += 256) {
        int2 p = pairs[i];
        int loc = atomicAdd(&lpos[p.y & 255], 1);
        srcs[loc] = p.x;
    }
}

// ---------------------------------------------------------------------------
// MFMA GEMM (layer 1): G[r][c] = dinv[r] * sum_k X[r][k]*W[k][c]
// 4 waves/block, wave = 16 rows x 128 cols; no LDS, no barriers (R8-proven).
// ---------------------------------------------------------------------------
__global__ __launch_bounds__(256) void k_gemm_mfma(const float* __restrict__ X,
                                                   const _Float16* __restrict__ WT,
                                                   const float* __restrict__ dinv,
                                                   _Float16* __restrict__ G, int n) {
    int tid = threadIdx.x;
    int wave = tid >> 6, lane = tid & 63;
    int q = lane >> 4, ln = lane & 15;
    int m0 = blockIdx.x * 64 + wave * 16;
    int mA = m0 + ln; if (mA >= n) mA = n - 1;   // clamp: harmless dup load
    const float* xrow = X + (size_t)mA * 128;

    floatx4 acc[8];
#pragma unroll
    for (int t = 0; t < 8; ++t) acc[t] = (floatx4){0.f, 0.f, 0.f, 0.f};

#pragma unroll
    for (int kc = 0; kc < 128; kc += 32) {
        half8 a;
        const float4* p = (const float4*)(xrow + kc + q * 8);
        float4 f0 = p[0], f1 = p[1];
        a[0] = (_Float16)f0.x; a[1] = (_Float16)f0.y;
        a[2] = (_Float16)f0.z; a[3] = (_Float16)f0.w;
        a[4] = (_Float16)f1.x; a[5] = (_Float16)f1.y;
        a[6] = (_Float16)f1.z; a[7] = (_Float16)f1.w;
#pragma unroll
        for (int t = 0; t < 8; ++t) {
            half8 b = *(const half8*)(WT + (size_t)(t * 16 + ln) * 128 + kc + q * 8);
            acc[t] = __builtin_amdgcn_mfma_f32_16x16x32_f16(a, b, acc[t], 0, 0, 0);
        }
    }

#pragma unroll
    for (int r = 0; r < 4; ++r) {
        int row = m0 + q * 4 + r;
        if (row < n) {
            float dv = dinv[row];
            _Float16* grow = G + (size_t)row * 128 + ln;
#pragma unroll
            for (int t = 0; t < 8; ++t)
                grow[t * 16] = (_Float16)(acc[t][r] * dv);
        }
    }
}

// ---------------------------------------------------------------------------
// Fused layer-1 gather + layer-2 GEMM:
//   z1 = relu(dinv*(g1[v] + sum g1[s]) + b1)  -> LDS (never global)
//   G2[v] = dinv[v] * (z1[v] @ W2)            -> MFMA, 16 nodes = one M-tile
// Block = 256 threads, 16 nodes. Gather: node = tid>>4, 16 lanes x half8.
// MFMA: wave w owns cols [w*32, w*32+32) (2 tiles); A from LDS (padded
// stride 136 halfs), B from WT2 (L1-resident).
// ---------------------------------------------------------------------------
__global__ __launch_bounds__(256) void k_gather_gemm(const _Float16* __restrict__ G,
                                                     const int* __restrict__ srcs,
                                                     const int* __restrict__ row_start,
                                                     const int* __restrict__ cnt,
                                                     const float* __restrict__ dinv,
                                                     const float* __restrict__ bias,
                                                     const _Float16* __restrict__ WT2,
                                                     _Float16* __restrict__ G2, int n) {
    __shared__ _Float16 zl[16 * 136];   // 16 node rows, padded stride
    int tid = threadIdx.x;
    int nl = tid >> 4;                  // local node 0..15
    int lane = tid & 15;
    int v = blockIdx.x * 16 + nl;
    const half8* G8 = (const half8*)G;

    half8 zo;
    if (v < n) {
        half8 self = G8[(size_t)v * 16 + lane];
        float acc[8], acc2[8];
#pragma unroll
        for (int j = 0; j < 8; ++j) { acc[j] = (float)self[j]; acc2[j] = 0.f; }

        int beg = row_start[v], deg = cnt[v];
        int e = 0;
        for (; e + 3 < deg; e += 4) {
            int s0 = srcs[beg + e];
            int s1 = srcs[beg + e + 1];
            int s2 = srcs[beg + e + 2];
            int s3 = srcs[beg + e + 3];
            half8 t0 = G8[(size_t)s0 * 16 + lane];
            half8 t1 = G8[(size_t)s1 * 16 + lane];
            half8 t2 = G8[(size_t)s2 * 16 + lane];
            half8 t3 = G8[(size_t)s3 * 16 + lane];
#pragma unroll
            for (int j = 0; j < 8; ++j) {
                acc[j]  += (float)t0[j] + (float)t1[j];
                acc2[j] += (float)t2[j] + (float)t3[j];
            }
        }
        for (; e < deg; ++e) {
            int s0 = srcs[beg + e];
            half8 t0 = G8[(size_t)s0 * 16 + lane];
#pragma unroll
            for (int j = 0; j < 8; ++j) acc[j] += (float)t0[j];
        }

        float dv = dinv[v];
        const float4* b4 = (const float4*)bias;
        float4 bb0 = b4[lane * 2], bb1 = b4[lane * 2 + 1];
        float bf[8] = {bb0.x, bb0.y, bb0.z, bb0.w, bb1.x, bb1.y, bb1.z, bb1.w};
#pragma unroll
        for (int j = 0; j < 8; ++j) {
            float z = dv * (acc[j] + acc2[j]) + bf[j];
            zo[j] = (_Float16)fmaxf(z, 0.f);
        }
    } else {
#pragma unroll
        for (int j = 0; j < 8; ++j) zo[j] = (_Float16)0.f;
    }
    *(half8*)(zl + nl * 136 + lane * 8) = zo;
    __syncthreads();

    // ---- MFMA: z1 (16x128, LDS) @ W2 (128x128) -> G2 rows
    int wave = tid >> 6, wl = tid & 63;
    int q = wl >> 4, ln = wl & 15;
    floatx4 acc[2];
    acc[0] = (floatx4){0.f, 0.f, 0.f, 0.f};
    acc[1] = (floatx4){0.f, 0.f, 0.f, 0.f};
#pragma unroll
    for (int kc = 0; kc < 128; kc += 32) {
        half8 a = *(const half8*)(zl + ln * 136 + kc + q * 8);
#pragma unroll
        for (int t = 0; t < 2; ++t) {
            int cb = wave * 32 + t * 16;
            half8 b = *(const half8*)(WT2 + (size_t)(cb + ln) * 128 + kc + q * 8);
            acc[t] = __builtin_amdgcn_mfma_f32_16x16x32_f16(a, b, acc[t], 0, 0, 0);
        }
    }
#pragma unroll
    for (int r = 0; r < 4; ++r) {
        int gv = blockIdx.x * 16 + q * 4 + r;
        if (gv < n) {
            float dv = dinv[gv];
#pragma unroll
            for (int t = 0; t < 2; ++t)
                G2[(size_t)gv * 128 + wave * 32 + t * 16 + ln] =
                    (_Float16)(acc[t][r] * dv);
        }
    }
}

// ---------------------------------------------------------------------------
// Layer-2 gather + bias + relu -> z2 (fp16). 16 lanes/node, half8.
// ---------------------------------------------------------------------------
__global__ __launch_bounds__(256) void k_gather_relu(const _Float16* __restrict__ G,
                                                     const int* __restrict__ srcs,
                                                     const int* __restrict__ row_start,
                                                     const int* __restrict__ cnt,
                                                     const float* __restrict__ dinv,
                                                     const float* __restrict__ bias,
                                                     _Float16* __restrict__ Z, int n) {
    int v = blockIdx.x * 16 + (threadIdx.x >> 4);
    int lane = threadIdx.x & 15;
    if (v >= n) return;
    const half8* G8 = (const half8*)G;

    half8 self = G8[(size_t)v * 16 + lane];
    float acc[8], acc2[8];
#pragma unroll
    for (int j = 0; j < 8; ++j) { acc[j] = (float)self[j]; acc2[j] = 0.f; }

    int beg = row_start[v], deg = cnt[v];
    int e = 0;
    for (; e + 3 < deg; e += 4) {
        int s0 = srcs[beg + e];
        int s1 = srcs[beg + e + 1];
        int s2 = srcs[beg + e + 2];
        int s3 = srcs[beg + e + 3];
        half8 t0 = G8[(size_t)s0 * 16 + lane];
        half8 t1 = G8[(size_t)s1 * 16 + lane];
        half8 t2 = G8[(size_t)s2 * 16 + lane];
        half8 t3 = G8[(size_t)s3 * 16 + lane];
#pragma unroll
        for (int j = 0; j < 8; ++j) {
            acc[j]  += (float)t0[j] + (float)t1[j];
            acc2[j] += (float)t2[j] + (float)t3[j];
        }
    }
    for (; e < deg; ++e) {
        int s0 = srcs[beg + e];
        half8 t0 = G8[(size_t)s0 * 16 + lane];
#pragma unroll
        for (int j = 0; j < 8; ++j) acc[j] += (float)t0[j];
    }

    float dv = dinv[v];
    const float4* b4 = (const float4*)bias;
    float4 bb0 = b4[lane * 2], bb1 = b4[lane * 2 + 1];
    float bf[8] = {bb0.x, bb0.y, bb0.z, bb0.w, bb1.x, bb1.y, bb1.z, bb1.w};
    half8 zo;
#pragma unroll
    for (int j = 0; j < 8; ++j) {
        float z = dv * (acc[j] + acc2[j]) + bf[j];
        zo[j] = (_Float16)fmaxf(z, 0.f);
    }
    ((half8*)Z)[(size_t)v * 16 + lane] = zo;
}

// ---------------------------------------------------------------------------
// Decode: out[e] = dot(Z[s_e], Z[d_e]) over 128 dims (fp16 rows, fp32 accum).
// ---------------------------------------------------------------------------
__global__ __launch_bounds__(256) void k_decode(const _Float16* __restrict__ Z,
                                                const int* __restrict__ eli,
                                                float* __restrict__ out, int el) {
    int sub = threadIdx.x >> 4, lane = threadIdx.x & 15;
    int e = blockIdx.x * 16 + sub;
    if (e >= el) return;
    int s = eli[e], d = eli[el + e];
    const half8* Z8 = (const half8*)Z;
    half8 a = Z8[(size_t)s * 16 + lane];
    half8 b = Z8[(size_t)d * 16 + lane];
    float dot = 0.f;
#pragma unroll
    for (int j = 0; j < 8; ++j) dot += (float)a[j] * (float)b[j];
#pragma unroll
    for (int off = 8; off; off >>= 1) dot += __shfl_down(dot, off, 16);
    if (lane == 0) out[e] = dot;
}

extern "C" void kernel_launch(void* const* d_in, const int* in_sizes, int n_in,
                              void* d_out, int out_size, void* d_ws, size_t ws_size,
                              hipStream_t stream) {
    const float* x  = (const float*)d_in[0];
    const int*  ei  = (const int*)d_in[1];
    const int*  eli = (const int*)d_in[2];
    const float* W1 = (const float*)d_in[3];
    const float* b1 = (const float*)d_in[4];
    const float* W2 = (const float*)d_in[5];
    const float* b2 = (const float*)d_in[6];
    float* out = (float*)d_out;

    const int N  = in_sizes[0] / 128;
    const int E  = in_sizes[1] / 2;
    const int EL = in_sizes[2] / 2;
    const int* src = ei;
    const int* dst = ei + E;
    const int NBK = (N + 255) >> BK_SHIFT;   // 391 for N=100000

    char* ws = (char*)d_ws;
    size_t off = 0;
    auto alloc = [&](size_t bytes) -> void* {
        void* p = ws + off;
        off += bytes;
        off = (off + 255) & ~(size_t)255;
        return p;
    };
    int*       cnt       = (int*)alloc((size_t)N * 4);
    int*       row_start = (int*)alloc((size_t)N * 4);
    float*     dinv      = (float*)alloc((size_t)N * 4);
    int*       bfill     = (int*)alloc(4096);
    _Float16*  WT1       = (_Float16*)alloc(128 * 128 * 2);
    _Float16*  WT2       = (_Float16*)alloc(128 * 128 * 2);
    int*       srcs      = (int*)alloc((size_t)NBK * SLAB_CAP * 4);
    int2*      pairs     = (int2*)alloc((size_t)NBK * SLAB_CAP * 8);
    _Float16*  buf0      = (_Float16*)alloc((size_t)N * 128 * 2);  // G1, then z2
    _Float16*  buf1      = (_Float16*)alloc((size_t)N * 128 * 2);  // G2

    // weight prep + slab cursor zero (independent of edge data)
    k_wprep<<<256, 128, 0, stream>>>(W1, W2, WT1, WT2);
    k_zero<<<2, 256, 0, stream>>>(bfill, 512);

    // CSR build: slab bucket sort (no count/scan pre-pass)
    k_bscatter<<<(E + BSC_EDGES - 1) / BSC_EDGES, 256, 0, stream>>>(src, dst, bfill, pairs, E, NBK);
    k_csr<<<NBK, 256, 0, stream>>>(pairs, bfill, row_start, cnt, dinv, srcs, N);

    // layer 1 GEMM: g1 = (x@W1)*dinv -> buf0 (fp16)
    k_gemm_mfma<<<(N + 63) / 64, 256, 0, stream>>>(x, WT1, dinv, buf0, N);
    // fused: z1 = relu(agg(g1)+b1) (LDS only) ; G2 = (z1@W2)*dinv -> buf1
    k_gather_gemm<<<(N + 15) / 16, 256, 0, stream>>>(buf0, srcs, row_start, cnt, dinv, b1, WT2, buf1, N);
    // layer 2 gather: z2 = relu(agg(G2)+b2) -> buf0
    k_gather_relu<<<(N + 15) / 16, 256, 0, stream>>>(buf1, srcs, row_start, cnt, dinv, b2, buf0, N);
    // decode
    k_decode<<<(EL + 15) / 16, 256, 0, stream>>>(buf0, eli, out, EL);
}

// Round 10
// 309.927 us; speedup vs baseline: 1.5653x; 1.0699x over previous
//
#include <hip/hip_runtime.h>
#include <hip/hip_bf16.h>
#include <hip/hip_fp16.h>

// ---------------------------------------------------------------------------
// GCN link predictor, fp16 intermediates + MFMA GEMMs (fp32 accumulate):
//   g1 = (X @ W1) * dinv[row]                    (MFMA GEMM, stored fp16)
//   z1 = relu(dinv*(g1[v] + sum g1[s]) + b1)     (gather; z1 stays in LDS)
//   g2 = (z1 @ W2) * dinv[row]                   (MFMA fused in gather1 epi)
//   z2 = relu(dinv*(g2[v] + sum g2[s]) + b2)     (gather)
//   out[e] = dot(z2[s], z2[d])
// CSR via slab bucket sort (bucket = dst>>8, CAP=5120 >> 15 sigma).
// R9 lesson: MFMA B-frags read WT from L1 while the gather streams 189 MB
// of random rows through the same L1 -> WT thrashes to L2 (~+21 µs). R10:
// stage WT in LDS (padded stride 136 halfs -> 2-way bank alias = free);
// gemm1 goes M=32/wave to halve LDS B traffic.
// ---------------------------------------------------------------------------

typedef _Float16 half8 __attribute__((ext_vector_type(8)));
typedef float floatx4 __attribute__((ext_vector_type(4)));

#define BK_SHIFT 8
#define BSC_EDGES 2048  // edges per block in binning scatter
#define SLAB_CAP 5120   // per-bucket slab capacity (mean 4092, sd 64)
#define WPAD 136        // padded LDS row stride (halfs) for weight tiles

__global__ __launch_bounds__(256) void k_zero(int* __restrict__ p, int n) {
    int i = blockIdx.x * 256 + threadIdx.x;
    if (i < n) p[i] = 0;
}

// ---- transpose + fp16-cast the two weight matrices: WT[c][k] = W[k][c]
__global__ __launch_bounds__(128) void k_wprep(const float* __restrict__ W1,
                                               const float* __restrict__ W2,
                                               _Float16* __restrict__ WT1,
                                               _Float16* __restrict__ WT2) {
    int b = blockIdx.x;               // 0..255
    const float* W = (b < 128) ? W1 : W2;
    _Float16* WT = (b < 128) ? WT1 : WT2;
    int k = b & 127;
    int c = threadIdx.x;
    WT[c * 128 + k] = (_Float16)W[k * 128 + c];
}

// ---- LDS-binned scatter of (src,dst) pairs into per-bucket slabs.
__global__ __launch_bounds__(256) void k_bscatter(const int* __restrict__ src,
                                                  const int* __restrict__ dst,
                                                  int* __restrict__ bfill,
                                                  int2* __restrict__ pairs,
                                                  int E, int nbk) {
    __shared__ int lcnt[1024];    // counts, then fill cursor (= lbase)
    __shared__ int delta[1024];   // slab_dest - lbase per bucket
    __shared__ int ssum[256];     // block-scan workspace
    __shared__ int2 stage[BSC_EDGES];
    int tid = threadIdx.x;
    int e0 = blockIdx.x * BSC_EDGES;
    int nloc = E - e0; if (nloc > BSC_EDGES) nloc = BSC_EDGES;

    for (int b = tid; b < nbk; b += 256) lcnt[b] = 0;
    __syncthreads();

    int d[BSC_EDGES / 256], s[BSC_EDGES / 256];
#pragma unroll
    for (int k = 0; k < BSC_EDGES / 256; ++k) {
        int e = e0 + k * 256 + tid;
        if (e < E) {
            d[k] = dst[e];
            s[k] = src[e];
            atomicAdd(&lcnt[d[k] >> BK_SHIFT], 1);
        } else d[k] = -1;
    }
    __syncthreads();

    const int gpb = (nbk + 255) >> 8;   // <=4 for nbk<=1024
    int c[4], mysum = 0;
    for (int t = 0; t < gpb; ++t) {
        int b = tid * gpb + t;
        c[t] = (b < nbk) ? lcnt[b] : 0;
        mysum += c[t];
    }
    ssum[tid] = mysum;
    __syncthreads();
    for (int off = 1; off < 256; off <<= 1) {
        int t = (tid >= off) ? ssum[tid - off] : 0;
        __syncthreads();
        ssum[tid] += t;
        __syncthreads();
    }
    int base = ssum[tid] - mysum;
    for (int t = 0; t < gpb; ++t) {
        int b = tid * gpb + t;
        if (b < nbk) {
            int g = c[t] ? atomicAdd(&bfill[b], c[t]) : 0;
            delta[b] = b * SLAB_CAP + g - base;   // slab dest - lbase
            lcnt[b] = base;                        // cursor starts at lbase
            base += c[t];
        }
    }
    __syncthreads();

#pragma unroll
    for (int k = 0; k < BSC_EDGES / 256; ++k) {
        if (d[k] >= 0) {
            int b = d[k] >> BK_SHIFT;
            int lp = atomicAdd(&lcnt[b], 1);
            int2 p; p.x = s[k]; p.y = d[k];
            stage[lp] = p;
        }
    }
    __syncthreads();

    for (int j = tid; j < nloc; j += 256) {
        int2 p = stage[j];
        pairs[delta[p.y >> BK_SHIFT] + j] = p;
    }
}

// ---- fused CSR build, one block per bucket slab (256 nodes)
__global__ __launch_bounds__(256) void k_csr(const int2* __restrict__ pairs,
                                             const int* __restrict__ bfill,
                                             int* __restrict__ row_start,
                                             int* __restrict__ cnt,
                                             float* __restrict__ dinv,
                                             int* __restrict__ srcs, int n) {
    __shared__ int lcnt[256];
    __shared__ int lpos[256];
    int tid = threadIdx.x;
    int b = blockIdx.x;
    lcnt[tid] = 0;
    __syncthreads();
    int beg = b * SLAB_CAP, end = beg + bfill[b];
    for (int i = beg + tid; i < end; i += 256)
        atomicAdd(&lcnt[pairs[i].y & 255], 1);
    __syncthreads();
    int c = lcnt[tid];
    lpos[tid] = c;
    __syncthreads();
    for (int off = 1; off < 256; off <<= 1) {
        int t = (tid >= off) ? lpos[tid - off] : 0;
        __syncthreads();
        lpos[tid] += t;
        __syncthreads();
    }
    int rs = beg + lpos[tid] - c;   // row start (slab-relative, gaps ok)
    int v = (b << BK_SHIFT) + tid;
    if (v < n) {
        row_start[v] = rs;
        cnt[v] = c;
        dinv[v] = rsqrtf((float)c + 1.0f);
    }
    __syncthreads();
    lpos[tid] = rs;                 // reuse as fill cursor
    __syncthreads();
    for (int i = beg + tid; i < end; i += 256) {
        int2 p = pairs[i];
        int loc = atomicAdd(&lpos[p.y & 255], 1);
        srcs[loc] = p.x;
    }
}

// ---------------------------------------------------------------------------
// MFMA GEMM (layer 1): G[r][c] = dinv[r] * sum_k X[r][k]*W[k][c]
// Block 256 thr = 4 waves, M=32/wave -> 128 rows/block. WT staged in LDS
// (padded stride WPAD -> ds_read_b128 2-way alias = free, L1-thrash immune).
// ---------------------------------------------------------------------------
__global__ __launch_bounds__(256) void k_gemm_mfma(const float* __restrict__ X,
                                                   const _Float16* __restrict__ WT,
                                                   const float* __restrict__ dinv,
                                                   _Float16* __restrict__ G, int n) {
    __shared__ _Float16 Wl[128 * WPAD];
    int tid = threadIdx.x;
    {
        const half8* w8 = (const half8*)WT;
#pragma unroll
        for (int i = 0; i < 8; ++i) {
            int idx = i * 256 + tid;
            int r = idx >> 4, cc = idx & 15;
            *(half8*)(Wl + r * WPAD + cc * 8) = w8[idx];
        }
    }
    __syncthreads();

    int wave = tid >> 6, lane = tid & 63;
    int q = lane >> 4, ln = lane & 15;
    int m0 = blockIdx.x * 128 + wave * 32;
    int mA0 = m0 + ln;      if (mA0 >= n) mA0 = n - 1;
    int mA1 = m0 + 16 + ln; if (mA1 >= n) mA1 = n - 1;
    const float* xr0 = X + (size_t)mA0 * 128;
    const float* xr1 = X + (size_t)mA1 * 128;

    floatx4 acc[2][8];
#pragma unroll
    for (int p = 0; p < 2; ++p)
#pragma unroll
        for (int t = 0; t < 8; ++t) acc[p][t] = (floatx4){0.f, 0.f, 0.f, 0.f};

#pragma unroll
    for (int kc = 0; kc < 128; kc += 32) {
        half8 a0, a1;
        {
            const float4* p0 = (const float4*)(xr0 + kc + q * 8);
            float4 f0 = p0[0], f1 = p0[1];
            a0[0] = (_Float16)f0.x; a0[1] = (_Float16)f0.y;
            a0[2] = (_Float16)f0.z; a0[3] = (_Float16)f0.w;
            a0[4] = (_Float16)f1.x; a0[5] = (_Float16)f1.y;
            a0[6] = (_Float16)f1.z; a0[7] = (_Float16)f1.w;
            const float4* p1 = (const float4*)(xr1 + kc + q * 8);
            float4 g0 = p1[0], g1 = p1[1];
            a1[0] = (_Float16)g0.x; a1[1] = (_Float16)g0.y;
            a1[2] = (_Float16)g0.z; a1[3] = (_Float16)g0.w;
            a1[4] = (_Float16)g1.x; a1[5] = (_Float16)g1.y;
            a1[6] = (_Float16)g1.z; a1[7] = (_Float16)g1.w;
        }
#pragma unroll
        for (int t = 0; t < 8; ++t) {
            half8 b = *(const half8*)(Wl + (size_t)(t * 16 + ln) * WPAD + kc + q * 8);
            acc[0][t] = __builtin_amdgcn_mfma_f32_16x16x32_f16(a0, b, acc[0][t], 0, 0, 0);
            acc[1][t] = __builtin_amdgcn_mfma_f32_16x16x32_f16(a1, b, acc[1][t], 0, 0, 0);
        }
    }

#pragma unroll
    for (int p = 0; p < 2; ++p) {
#pragma unroll
        for (int r = 0; r < 4; ++r) {
            int row = m0 + p * 16 + q * 4 + r;
            if (row < n) {
                float dv = dinv[row];
                _Float16* grow = G + (size_t)row * 128 + ln;
#pragma unroll
                for (int t = 0; t < 8; ++t)
                    grow[t * 16] = (_Float16)(acc[p][t][r] * dv);
            }
        }
    }
}

// ---------------------------------------------------------------------------
// Fused layer-1 gather + layer-2 GEMM. WT2 staged in LDS at kernel start
// (burst, shares the gather->MFMA barrier); z1 lives only in LDS.
// ---------------------------------------------------------------------------
__global__ __launch_bounds__(256) void k_gather_gemm(const _Float16* __restrict__ G,
                                                     const int* __restrict__ srcs,
                                                     const int* __restrict__ row_start,
                                                     const int* __restrict__ cnt,
                                                     const float* __restrict__ dinv,
                                                     const float* __restrict__ bias,
                                                     const _Float16* __restrict__ WT2,
                                                     _Float16* __restrict__ G2, int n) {
    __shared__ _Float16 Wl[128 * WPAD];  // staged WT2
    __shared__ _Float16 zl[16 * WPAD];   // 16 z1 rows
    int tid = threadIdx.x;

    // stage WT2 -> LDS (coalesced burst; completes at the barrier below)
    {
        const half8* w8 = (const half8*)WT2;
#pragma unroll
        for (int i = 0; i < 8; ++i) {
            int idx = i * 256 + tid;
            int r = idx >> 4, cc = idx & 15;
            *(half8*)(Wl + r * WPAD + cc * 8) = w8[idx];
        }
    }

    int nl = tid >> 4;                  // local node 0..15
    int lane = tid & 15;
    int v = blockIdx.x * 16 + nl;
    const half8* G8 = (const half8*)G;

    half8 zo;
    if (v < n) {
        half8 self = G8[(size_t)v * 16 + lane];
        float acc[8], acc2[8];
#pragma unroll
        for (int j = 0; j < 8; ++j) { acc[j] = (float)self[j]; acc2[j] = 0.f; }

        int beg = row_start[v], deg = cnt[v];
        int e = 0;
        for (; e + 3 < deg; e += 4) {
            int s0 = srcs[beg + e];
            int s1 = srcs[beg + e + 1];
            int s2 = srcs[beg + e + 2];
            int s3 = srcs[beg + e + 3];
            half8 t0 = G8[(size_t)s0 * 16 + lane];
            half8 t1 = G8[(size_t)s1 * 16 + lane];
            half8 t2 = G8[(size_t)s2 * 16 + lane];
            half8 t3 = G8[(size_t)s3 * 16 + lane];
#pragma unroll
            for (int j = 0; j < 8; ++j) {
                acc[j]  += (float)t0[j] + (float)t1[j];
                acc2[j] += (float)t2[j] + (float)t3[j];
            }
        }
        for (; e < deg; ++e) {
            int s0 = srcs[beg + e];
            half8 t0 = G8[(size_t)s0 * 16 + lane];
#pragma unroll
            for (int j = 0; j < 8; ++j) acc[j] += (float)t0[j];
        }

        float dv = dinv[v];
        const float4* b4 = (const float4*)bias;
        float4 bb0 = b4[lane * 2], bb1 = b4[lane * 2 + 1];
        float bf[8] = {bb0.x, bb0.y, bb0.z, bb0.w, bb1.x, bb1.y, bb1.z, bb1.w};
#pragma unroll
        for (int j = 0; j < 8; ++j) {
            float z = dv * (acc[j] + acc2[j]) + bf[j];
            zo[j] = (_Float16)fmaxf(z, 0.f);
        }
    } else {
#pragma unroll
        for (int j = 0; j < 8; ++j) zo[j] = (_Float16)0.f;
    }
    *(half8*)(zl + nl * WPAD + lane * 8) = zo;
    __syncthreads();

    // ---- MFMA: z1 (16x128, LDS) @ W2 (LDS) -> G2 rows
    int wave = tid >> 6, wl = tid & 63;
    int q = wl >> 4, ln = wl & 15;
    floatx4 acc[2];
    acc[0] = (floatx4){0.f, 0.f, 0.f, 0.f};
    acc[1] = (floatx4){0.f, 0.f, 0.f, 0.f};
#pragma unroll
    for (int kc = 0; kc < 128; kc += 32) {
        half8 a = *(const half8*)(zl + ln * WPAD + kc + q * 8);
#pragma unroll
        for (int t = 0; t < 2; ++t) {
            int cb = wave * 32 + t * 16;
            half8 b = *(const half8*)(Wl + (size_t)(cb + ln) * WPAD + kc + q * 8);
            acc[t] = __builtin_amdgcn_mfma_f32_16x16x32_f16(a, b, acc[t], 0, 0, 0);
        }
    }
#pragma unroll
    for (int r = 0; r < 4; ++r) {
        int gv = blockIdx.x * 16 + q * 4 + r;
        if (gv < n) {
            float dv = dinv[gv];
#pragma unroll
            for (int t = 0; t < 2; ++t)
                G2[(size_t)gv * 128 + wave * 32 + t * 16 + ln] =
                    (_Float16)(acc[t][r] * dv);
        }
    }
}

// ---------------------------------------------------------------------------
// Layer-2 gather + bias + relu -> z2 (fp16). 16 lanes/node, half8.
// ---------------------------------------------------------------------------
__global__ __launch_bounds__(256) void k_gather_relu(const _Float16* __restrict__ G,
                                                     const int* __restrict__ srcs,
                                                     const int* __restrict__ row_start,
                                                     const int* __restrict__ cnt,
                                                     const float* __restrict__ dinv,
                                                     const float* __restrict__ bias,
                                                     _Float16* __restrict__ Z, int n) {
    int v = blockIdx.x * 16 + (threadIdx.x >> 4);
    int lane = threadIdx.x & 15;
    if (v >= n) return;
    const half8* G8 = (const half8*)G;

    half8 self = G8[(size_t)v * 16 + lane];
    float acc[8], acc2[8];
#pragma unroll
    for (int j = 0; j < 8; ++j) { acc[j] = (float)self[j]; acc2[j] = 0.f; }

    int beg = row_start[v], deg = cnt[v];
    int e = 0;
    for (; e + 3 < deg; e += 4) {
        int s0 = srcs[beg + e];
        int s1 = srcs[beg + e + 1];
        int s2 = srcs[beg + e + 2];
        int s3 = srcs[beg + e + 3];
        half8 t0 = G8[(size_t)s0 * 16 + lane];
        half8 t1 = G8[(size_t)s1 * 16 + lane];
        half8 t2 = G8[(size_t)s2 * 16 + lane];
        half8 t3 = G8[(size_t)s3 * 16 + lane];
#pragma unroll
        for (int j = 0; j < 8; ++j) {
            acc[j]  += (float)t0[j] + (float)t1[j];
            acc2[j] += (float)t2[j] + (float)t3[j];
        }
    }
    for (; e < deg; ++e) {
        int s0 = srcs[beg + e];
        half8 t0 = G8[(size_t)s0 * 16 + lane];
#pragma unroll
        for (int j = 0; j < 8; ++j) acc[j] += (float)t0[j];
    }

    float dv = dinv[v];
    const float4* b4 = (const float4*)bias;
    float4 bb0 = b4[lane * 2], bb1 = b4[lane * 2 + 1];
    float bf[8] = {bb0.x, bb0.y, bb0.z, bb0.w, bb1.x, bb1.y, bb1.z, bb1.w};
    half8 zo;
#pragma unroll
    for (int j = 0; j < 8; ++j) {
        float z = dv * (acc[j] + acc2[j]) + bf[j];
        zo[j] = (_Float16)fmaxf(z, 0.f);
    }
    ((half8*)Z)[(size_t)v * 16 + lane] = zo;
}

// ---------------------------------------------------------------------------
// Decode: out[e] = dot(Z[s_e], Z[d_e]) over 128 dims (fp16 rows, fp32 accum).
// ---------------------------------------------------------------------------
__global__ __launch_bounds__(256) void k_decode(const _Float16* __restrict__ Z,
                                                const int* __restrict__ eli,
                                                float* __restrict__ out, int el) {
    int sub = threadIdx.x >> 4, lane = threadIdx.x & 15;
    int e = blockIdx.x * 16 + sub;
    if (e >= el) return;
    int s = eli[e], d = eli[el + e];
    const half8* Z8 = (const half8*)Z;
    half8 a = Z8[(size_t)s * 16 + lane];
    half8 b = Z8[(size_t)d * 16 + lane];
    float dot = 0.f;
#pragma unroll
    for (int j = 0; j < 8; ++j) dot += (float)a[j] * (float)b[j];
#pragma unroll
    for (int off = 8; off; off >>= 1) dot += __shfl_down(dot, off, 16);
    if (lane == 0) out[e] = dot;
}

extern "C" void kernel_launch(void* const* d_in, const int* in_sizes, int n_in,
                              void* d_out, int out_size, void* d_ws, size_t ws_size,
                              hipStream_t stream) {
    const float* x  = (const float*)d_in[0];
    const int*  ei  = (const int*)d_in[1];
    const int*  eli = (const int*)d_in[2];
    const float* W1 = (const float*)d_in[3];
    const float* b1 = (const float*)d_in[4];
    const float* W2 = (const float*)d_in[5];
    const float* b2 = (const float*)d_in[6];
    float* out = (float*)d_out;

    const int N  = in_sizes[0] / 128;
    const int E  = in_sizes[1] / 2;
    const int EL = in_sizes[2] / 2;
    const int* src = ei;
    const int* dst = ei + E;
    const int NBK = (N + 255) >> BK_SHIFT;   // 391 for N=100000

    char* ws = (char*)d_ws;
    size_t off = 0;
    auto alloc = [&](size_t bytes) -> void* {
        void* p = ws + off;
        off += bytes;
        off = (off + 255) & ~(size_t)255;
        return p;
    };
    int*       cnt       = (int*)alloc((size_t)N * 4);
    int*       row_start = (int*)alloc((size_t)N * 4);
    float*     dinv      = (float*)alloc((size_t)N * 4);
    int*       bfill     = (int*)alloc(4096);
    _Float16*  WT1       = (_Float16*)alloc(128 * 128 * 2);
    _Float16*  WT2       = (_Float16*)alloc(128 * 128 * 2);
    int*       srcs      = (int*)alloc((size_t)NBK * SLAB_CAP * 4);
    int2*      pairs     = (int2*)alloc((size_t)NBK * SLAB_CAP * 8);
    _Float16*  buf0      = (_Float16*)alloc((size_t)N * 128 * 2);  // G1, then z2
    _Float16*  buf1      = (_Float16*)alloc((size_t)N * 128 * 2);  // G2

    // weight prep + slab cursor zero (independent of edge data)
    k_wprep<<<256, 128, 0, stream>>>(W1, W2, WT1, WT2);
    k_zero<<<2, 256, 0, stream>>>(bfill, 512);

    // CSR build: slab bucket sort (no count/scan pre-pass)
    k_bscatter<<<(E + BSC_EDGES - 1) / BSC_EDGES, 256, 0, stream>>>(src, dst, bfill, pairs, E, NBK);
    k_csr<<<NBK, 256, 0, stream>>>(pairs, bfill, row_start, cnt, dinv, srcs, N);

    // layer 1 GEMM: g1 = (x@W1)*dinv -> buf0 (fp16)
    k_gemm_mfma<<<(N + 127) / 128, 256, 0, stream>>>(x, WT1, dinv, buf0, N);
    // fused: z1 = relu(agg(g1)+b1) (LDS only) ; G2 = (z1@W2)*dinv -> buf1
    k_gather_gemm<<<(N + 15) / 16, 256, 0, stream>>>(buf0, srcs, row_start, cnt, dinv, b1, WT2, buf1, N);
    // layer 2 gather: z2 = relu(agg(G2)+b2) -> buf0
    k_gather_relu<<<(N + 15) / 16, 256, 0, stream>>>(buf1, srcs, row_start, cnt, dinv, b2, buf0, N);
    // decode
    k_decode<<<(EL + 15) / 16, 256, 0, stream>>>(buf0, eli, out, EL);
}

// Round 11
// 309.594 us; speedup vs baseline: 1.5670x; 1.0011x over previous
//
#include <hip/hip_runtime.h>
#include <hip/hip_bf16.h>
#include <hip/hip_fp16.h>

// ---------------------------------------------------------------------------
// GCN link predictor, fp16 intermediates + MFMA GEMMs (fp32 accumulate):
//   g1 = (X @ W1) * dinv[row]                    (MFMA GEMM, stored fp16)
//   z1 = relu(dinv*(g1[v] + sum g1[s]) + b1)     (gather; z1 stays in LDS)
//   g2 = (z1 @ W2) * dinv[row]                   (MFMA fused in gather1 epi)
//   z2 = relu(dinv*(g2[v] + sum g2[s]) + b2)     (gather)
//   out[e] = dot(z2[s], z2[d])
// CSR via slab bucket sort (bucket = dst>>8, CAP=5120 >> 15 sigma).
// R10 lesson: fused-kernel slowdown is NOT L1 thrash of W2 (LDS staging
// didn't fix it) -- it's the barrier turning Poisson-degree variance into a
// per-block max, plus serialized staging. R11: W2 fragments live in VGPRs
// (32/lane, loaded once), LDS down to 4.6 KB, and node slots are pulled
// dynamically from an LDS cursor so block gather time ~= mean, not max.
// ---------------------------------------------------------------------------

typedef _Float16 half8 __attribute__((ext_vector_type(8)));
typedef float floatx4 __attribute__((ext_vector_type(4)));

#define BK_SHIFT 8
#define BSC_EDGES 2048  // edges per block in binning scatter
#define SLAB_CAP 5120   // per-bucket slab capacity (mean 4092, sd 64)
#define WPAD 136        // padded LDS row stride (halfs)

// ---- transpose + fp16-cast weights; blocks 0..3 also zero bfill
__global__ __launch_bounds__(128) void k_wprep(const float* __restrict__ W1,
                                               const float* __restrict__ W2,
                                               _Float16* __restrict__ WT1,
                                               _Float16* __restrict__ WT2,
                                               int* __restrict__ bfill) {
    int b = blockIdx.x;               // 0..255
    const float* W = (b < 128) ? W1 : W2;
    _Float16* WT = (b < 128) ? WT1 : WT2;
    int k = b & 127;
    int c = threadIdx.x;
    WT[c * 128 + k] = (_Float16)W[k * 128 + c];
    if (b < 4) bfill[b * 128 + c] = 0;   // 512 ints >= NBK
}

// ---- LDS-binned scatter of (src,dst) pairs into per-bucket slabs.
__global__ __launch_bounds__(256) void k_bscatter(const int* __restrict__ src,
                                                  const int* __restrict__ dst,
                                                  int* __restrict__ bfill,
                                                  int2* __restrict__ pairs,
                                                  int E, int nbk) {
    __shared__ int lcnt[1024];    // counts, then fill cursor (= lbase)
    __shared__ int delta[1024];   // slab_dest - lbase per bucket
    __shared__ int ssum[256];     // block-scan workspace
    __shared__ int2 stage[BSC_EDGES];
    int tid = threadIdx.x;
    int e0 = blockIdx.x * BSC_EDGES;
    int nloc = E - e0; if (nloc > BSC_EDGES) nloc = BSC_EDGES;

    for (int b = tid; b < nbk; b += 256) lcnt[b] = 0;
    __syncthreads();

    int d[BSC_EDGES / 256], s[BSC_EDGES / 256];
#pragma unroll
    for (int k = 0; k < BSC_EDGES / 256; ++k) {
        int e = e0 + k * 256 + tid;
        if (e < E) {
            d[k] = dst[e];
            s[k] = src[e];
            atomicAdd(&lcnt[d[k] >> BK_SHIFT], 1);
        } else d[k] = -1;
    }
    __syncthreads();

    const int gpb = (nbk + 255) >> 8;   // <=4 for nbk<=1024
    int c[4], mysum = 0;
    for (int t = 0; t < gpb; ++t) {
        int b = tid * gpb + t;
        c[t] = (b < nbk) ? lcnt[b] : 0;
        mysum += c[t];
    }
    ssum[tid] = mysum;
    __syncthreads();
    for (int off = 1; off < 256; off <<= 1) {
        int t = (tid >= off) ? ssum[tid - off] : 0;
        __syncthreads();
        ssum[tid] += t;
        __syncthreads();
    }
    int base = ssum[tid] - mysum;
    for (int t = 0; t < gpb; ++t) {
        int b = tid * gpb + t;
        if (b < nbk) {
            int g = c[t] ? atomicAdd(&bfill[b], c[t]) : 0;
            delta[b] = b * SLAB_CAP + g - base;   // slab dest - lbase
            lcnt[b] = base;                        // cursor starts at lbase
            base += c[t];
        }
    }
    __syncthreads();

#pragma unroll
    for (int k = 0; k < BSC_EDGES / 256; ++k) {
        if (d[k] >= 0) {
            int b = d[k] >> BK_SHIFT;
            int lp = atomicAdd(&lcnt[b], 1);
            int2 p; p.x = s[k]; p.y = d[k];
            stage[lp] = p;
        }
    }
    __syncthreads();

    for (int j = tid; j < nloc; j += 256) {
        int2 p = stage[j];
        pairs[delta[p.y >> BK_SHIFT] + j] = p;
    }
}

// ---- fused CSR build, one block per bucket slab (256 nodes)
__global__ __launch_bounds__(256) void k_csr(const int2* __restrict__ pairs,
                                             const int* __restrict__ bfill,
                                             int* __restrict__ row_start,
                                             int* __restrict__ cnt,
                                             float* __restrict__ dinv,
                                             int* __restrict__ srcs, int n) {
    __shared__ int lcnt[256];
    __shared__ int lpos[256];
    int tid = threadIdx.x;
    int b = blockIdx.x;
    lcnt[tid] = 0;
    __syncthreads();
    int beg = b * SLAB_CAP, end = beg + bfill[b];
    for (int i = beg + tid; i < end; i += 256)
        atomicAdd(&lcnt[pairs[i].y & 255], 1);
    __syncthreads();
    int c = lcnt[tid];
    lpos[tid] = c;
    __syncthreads();
    for (int off = 1; off < 256; off <<= 1) {
        int t = (tid >= off) ? lpos[tid - off] : 0;
        __syncthreads();
        lpos[tid] += t;
        __syncthreads();
    }
    int rs = beg + lpos[tid] - c;   // row start (slab-relative, gaps ok)
    int v = (b << BK_SHIFT) + tid;
    if (v < n) {
        row_start[v] = rs;
        cnt[v] = c;
        dinv[v] = rsqrtf((float)c + 1.0f);
    }
    __syncthreads();
    lpos[tid] = rs;                 // reuse as fill cursor
    __syncthreads();
    for (int i = beg + tid; i < end; i += 256) {
        int2 p = pairs[i];
        int loc = atomicAdd(&lpos[p.y & 255], 1);
        srcs[loc] = p.x;
    }
}

// ---------------------------------------------------------------------------
// MFMA GEMM (layer 1): G[r][c] = dinv[r] * sum_k X[r][k]*W[k][c]
// Block 256 thr = 4 waves, M=32/wave -> 128 rows/block. WT staged in LDS.
// ---------------------------------------------------------------------------
__global__ __launch_bounds__(256) void k_gemm_mfma(const float* __restrict__ X,
                                                   const _Float16* __restrict__ WT,
                                                   const float* __restrict__ dinv,
                                                   _Float16* __restrict__ G, int n) {
    __shared__ _Float16 Wl[128 * WPAD];
    int tid = threadIdx.x;
    {
        const half8* w8 = (const half8*)WT;
#pragma unroll
        for (int i = 0; i < 8; ++i) {
            int idx = i * 256 + tid;
            int r = idx >> 4, cc = idx & 15;
            *(half8*)(Wl + r * WPAD + cc * 8) = w8[idx];
        }
    }
    __syncthreads();

    int wave = tid >> 6, lane = tid & 63;
    int q = lane >> 4, ln = lane & 15;
    int m0 = blockIdx.x * 128 + wave * 32;
    int mA0 = m0 + ln;      if (mA0 >= n) mA0 = n - 1;
    int mA1 = m0 + 16 + ln; if (mA1 >= n) mA1 = n - 1;
    const float* xr0 = X + (size_t)mA0 * 128;
    const float* xr1 = X + (size_t)mA1 * 128;

    floatx4 acc[2][8];
#pragma unroll
    for (int p = 0; p < 2; ++p)
#pragma unroll
        for (int t = 0; t < 8; ++t) acc[p][t] = (floatx4){0.f, 0.f, 0.f, 0.f};

#pragma unroll
    for (int kc = 0; kc < 128; kc += 32) {
        half8 a0, a1;
        {
            const float4* p0 = (const float4*)(xr0 + kc + q * 8);
            float4 f0 = p0[0], f1 = p0[1];
            a0[0] = (_Float16)f0.x; a0[1] = (_Float16)f0.y;
            a0[2] = (_Float16)f0.z; a0[3] = (_Float16)f0.w;
            a0[4] = (_Float16)f1.x; a0[5] = (_Float16)f1.y;
            a0[6] = (_Float16)f1.z; a0[7] = (_Float16)f1.w;
            const float4* p1 = (const float4*)(xr1 + kc + q * 8);
            float4 g0 = p1[0], g1 = p1[1];
            a1[0] = (_Float16)g0.x; a1[1] = (_Float16)g0.y;
            a1[2] = (_Float16)g0.z; a1[3] = (_Float16)g0.w;
            a1[4] = (_Float16)g1.x; a1[5] = (_Float16)g1.y;
            a1[6] = (_Float16)g1.z; a1[7] = (_Float16)g1.w;
        }
#pragma unroll
        for (int t = 0; t < 8; ++t) {
            half8 b = *(const half8*)(Wl + (size_t)(t * 16 + ln) * WPAD + kc + q * 8);
            acc[0][t] = __builtin_amdgcn_mfma_f32_16x16x32_f16(a0, b, acc[0][t], 0, 0, 0);
            acc[1][t] = __builtin_amdgcn_mfma_f32_16x16x32_f16(a1, b, acc[1][t], 0, 0, 0);
        }
    }

#pragma unroll
    for (int p = 0; p < 2; ++p) {
#pragma unroll
        for (int r = 0; r < 4; ++r) {
            int row = m0 + p * 16 + q * 4 + r;
            if (row < n) {
                float dv = dinv[row];
                _Float16* grow = G + (size_t)row * 128 + ln;
#pragma unroll
                for (int t = 0; t < 8; ++t)
                    grow[t * 16] = (_Float16)(acc[p][t][r] * dv);
            }
        }
    }
}

// ---------------------------------------------------------------------------
// Fused layer-1 gather + layer-2 GEMM.
// W2 fragments in VGPRs (8 x half8 per lane, loaded once -- thrash-immune).
// Node slots pulled dynamically from an LDS cursor (balances Poisson degree
// variance across the block). z1 lives only in LDS (16 x WPAD).
// ---------------------------------------------------------------------------
__global__ __launch_bounds__(256, 4) void k_gather_gemm(const _Float16* __restrict__ G,
                                                        const int* __restrict__ srcs,
                                                        const int* __restrict__ row_start,
                                                        const int* __restrict__ cnt,
                                                        const float* __restrict__ dinv,
                                                        const float* __restrict__ bias,
                                                        const _Float16* __restrict__ WT2,
                                                        _Float16* __restrict__ G2, int n) {
    __shared__ _Float16 zl[16 * WPAD];   // 16 z1 rows
    __shared__ int cursor;
    int tid = threadIdx.x;
    int wave = tid >> 6, wl = tid & 63;
    int q = wl >> 4, ln = wl & 15;

    // B fragments -> registers (wave w owns cols [w*32, w*32+32))
    half8 bfr[4][2];
#pragma unroll
    for (int kq = 0; kq < 4; ++kq)
#pragma unroll
        for (int t = 0; t < 2; ++t)
            bfr[kq][t] = *(const half8*)(WT2 +
                (size_t)(wave * 32 + t * 16 + ln) * 128 + kq * 32 + q * 8);

    if (tid == 0) cursor = 0;
    __syncthreads();

    int lane = tid & 15;                // lane within 16-lane node group
    const half8* G8 = (const half8*)G;
    const float4* b4 = (const float4*)bias;

    for (;;) {
        int slot = 0;
        if (lane == 0) slot = atomicAdd(&cursor, 1);
        slot = __shfl(slot, 0, 16);
        if (slot >= 16) break;
        int v = blockIdx.x * 16 + slot;
        half8 zo;
        if (v < n) {
            half8 self = G8[(size_t)v * 16 + lane];
            float acc[8], acc2[8];
#pragma unroll
            for (int j = 0; j < 8; ++j) { acc[j] = (float)self[j]; acc2[j] = 0.f; }

            int beg = row_start[v], deg = cnt[v];
            int e = 0;
            for (; e + 3 < deg; e += 4) {
                int s0 = srcs[beg + e];
                int s1 = srcs[beg + e + 1];
                int s2 = srcs[beg + e + 2];
                int s3 = srcs[beg + e + 3];
                half8 t0 = G8[(size_t)s0 * 16 + lane];
                half8 t1 = G8[(size_t)s1 * 16 + lane];
                half8 t2 = G8[(size_t)s2 * 16 + lane];
                half8 t3 = G8[(size_t)s3 * 16 + lane];
#pragma unroll
                for (int j = 0; j < 8; ++j) {
                    acc[j]  += (float)t0[j] + (float)t1[j];
                    acc2[j] += (float)t2[j] + (float)t3[j];
                }
            }
            for (; e < deg; ++e) {
                int s0 = srcs[beg + e];
                half8 t0 = G8[(size_t)s0 * 16 + lane];
#pragma unroll
                for (int j = 0; j < 8; ++j) acc[j] += (float)t0[j];
            }

            float dv = dinv[v];
            float4 bb0 = b4[lane * 2], bb1 = b4[lane * 2 + 1];
            float bf[8] = {bb0.x, bb0.y, bb0.z, bb0.w, bb1.x, bb1.y, bb1.z, bb1.w};
#pragma unroll
            for (int j = 0; j < 8; ++j) {
                float z = dv * (acc[j] + acc2[j]) + bf[j];
                zo[j] = (_Float16)fmaxf(z, 0.f);
            }
        } else {
#pragma unroll
            for (int j = 0; j < 8; ++j) zo[j] = (_Float16)0.f;
        }
        *(half8*)(zl + slot * WPAD + lane * 8) = zo;
    }
    __syncthreads();

    // ---- MFMA: z1 (16x128, LDS) @ W2 (registers) -> G2 rows
    floatx4 acc[2];
    acc[0] = (floatx4){0.f, 0.f, 0.f, 0.f};
    acc[1] = (floatx4){0.f, 0.f, 0.f, 0.f};
#pragma unroll
    for (int kq = 0; kq < 4; ++kq) {
        half8 a = *(const half8*)(zl + ln * WPAD + kq * 32 + q * 8);
        acc[0] = __builtin_amdgcn_mfma_f32_16x16x32_f16(a, bfr[kq][0], acc[0], 0, 0, 0);
        acc[1] = __builtin_amdgcn_mfma_f32_16x16x32_f16(a, bfr[kq][1], acc[1], 0, 0, 0);
    }
#pragma unroll
    for (int r = 0; r < 4; ++r) {
        int gv = blockIdx.x * 16 + q * 4 + r;
        if (gv < n) {
            float dv = dinv[gv];
#pragma unroll
            for (int t = 0; t < 2; ++t)
                G2[(size_t)gv * 128 + wave * 32 + t * 16 + ln] =
                    (_Float16)(acc[t][r] * dv);
        }
    }
}

// ---------------------------------------------------------------------------
// Layer-2 gather + bias + relu -> z2 (fp16). 16 lanes/node, half8.
// ---------------------------------------------------------------------------
__global__ __launch_bounds__(256) void k_gather_relu(const _Float16* __restrict__ G,
                                                     const int* __restrict__ srcs,
                                                     const int* __restrict__ row_start,
                                                     const int* __restrict__ cnt,
                                                     const float* __restrict__ dinv,
                                                     const float* __restrict__ bias,
                                                     _Float16* __restrict__ Z, int n) {
    int v = blockIdx.x * 16 + (threadIdx.x >> 4);
    int lane = threadIdx.x & 15;
    if (v >= n) return;
    const half8* G8 = (const half8*)G;

    half8 self = G8[(size_t)v * 16 + lane];
    float acc[8], acc2[8];
#pragma unroll
    for (int j = 0; j < 8; ++j) { acc[j] = (float)self[j]; acc2[j] = 0.f; }

    int beg = row_start[v], deg = cnt[v];
    int e = 0;
    for (; e + 3 < deg; e += 4) {
        int s0 = srcs[beg + e];
        int s1 = srcs[beg + e + 1];
        int s2 = srcs[beg + e + 2];
        int s3 = srcs[beg + e + 3];
        half8 t0 = G8[(size_t)s0 * 16 + lane];
        half8 t1 = G8[(size_t)s1 * 16 + lane];
        half8 t2 = G8[(size_t)s2 * 16 + lane];
        half8 t3 = G8[(size_t)s3 * 16 + lane];
#pragma unroll
        for (int j = 0; j < 8; ++j) {
            acc[j]  += (float)t0[j] + (float)t1[j];
            acc2[j] += (float)t2[j] + (float)t3[j];
        }
    }
    for (; e < deg; ++e) {
        int s0 = srcs[beg + e];
        half8 t0 = G8[(size_t)s0 * 16 + lane];
#pragma unroll
        for (int j = 0; j < 8; ++j) acc[j] += (float)t0[j];
    }

    float dv = dinv[v];
    const float4* b4 = (const float4*)bias;
    float4 bb0 = b4[lane * 2], bb1 = b4[lane * 2 + 1];
    float bf[8] = {bb0.x, bb0.y, bb0.z, bb0.w, bb1.x, bb1.y, bb1.z, bb1.w};
    half8 zo;
#pragma unroll
    for (int j = 0; j < 8; ++j) {
        float z = dv * (acc[j] + acc2[j]) + bf[j];
        zo[j] = (_Float16)fmaxf(z, 0.f);
    }
    ((half8*)Z)[(size_t)v * 16 + lane] = zo;
}

// ---------------------------------------------------------------------------
// Decode: out[e] = dot(Z[s_e], Z[d_e]) over 128 dims (fp16 rows, fp32 accum).
// ---------------------------------------------------------------------------
__global__ __launch_bounds__(256) void k_decode(const _Float16* __restrict__ Z,
                                                const int* __restrict__ eli,
                                                float* __restrict__ out, int el) {
    int sub = threadIdx.x >> 4, lane = threadIdx.x & 15;
    int e = blockIdx.x * 16 + sub;
    if (e >= el) return;
    int s = eli[e], d = eli[el + e];
    const half8* Z8 = (const half8*)Z;
    half8 a = Z8[(size_t)s * 16 + lane];
    half8 b = Z8[(size_t)d * 16 + lane];
    float dot = 0.f;
#pragma unroll
    for (int j = 0; j < 8; ++j) dot += (float)a[j] * (float)b[j];
#pragma unroll
    for (int off = 8; off; off >>= 1) dot += __shfl_down(dot, off, 16);
    if (lane == 0) out[e] = dot;
}

extern "C" void kernel_launch(void* const* d_in, const int* in_sizes, int n_in,
                              void* d_out, int out_size, void* d_ws, size_t ws_size,
                              hipStream_t stream) {
    const float* x  = (const float*)d_in[0];
    const int*  ei  = (const int*)d_in[1];
    const int*  eli = (const int*)d_in[2];
    const float* W1 = (const float*)d_in[3];
    const float* b1 = (const float*)d_in[4];
    const float* W2 = (const float*)d_in[5];
    const float* b2 = (const float*)d_in[6];
    float* out = (float*)d_out;

    const int N  = in_sizes[0] / 128;
    const int E  = in_sizes[1] / 2;
    const int EL = in_sizes[2] / 2;
    const int* src = ei;
    const int* dst = ei + E;
    const int NBK = (N + 255) >> BK_SHIFT;   // 391 for N=100000

    char* ws = (char*)d_ws;
    size_t off = 0;
    auto alloc = [&](size_t bytes) -> void* {
        void* p = ws + off;
        off += bytes;
        off = (off + 255) & ~(size_t)255;
        return p;
    };
    int*       cnt       = (int*)alloc((size_t)N * 4);
    int*       row_start = (int*)alloc((size_t)N * 4);
    float*     dinv      = (float*)alloc((size_t)N * 4);
    int*       bfill     = (int*)alloc(4096);
    _Float16*  WT1       = (_Float16*)alloc(128 * 128 * 2);
    _Float16*  WT2       = (_Float16*)alloc(128 * 128 * 2);
    int*       srcs      = (int*)alloc((size_t)NBK * SLAB_CAP * 4);
    int2*      pairs     = (int2*)alloc((size_t)NBK * SLAB_CAP * 8);
    _Float16*  buf0      = (_Float16*)alloc((size_t)N * 128 * 2);  // G1, then z2
    _Float16*  buf1      = (_Float16*)alloc((size_t)N * 128 * 2);  // G2

    // weight prep + bfill zero (one launch)
    k_wprep<<<256, 128, 0, stream>>>(W1, W2, WT1, WT2, bfill);

    // CSR build: slab bucket sort (no count/scan pre-pass)
    k_bscatter<<<(E + BSC_EDGES - 1) / BSC_EDGES, 256, 0, stream>>>(src, dst, bfill, pairs, E, NBK);
    k_csr<<<NBK, 256, 0, stream>>>(pairs, bfill, row_start, cnt, dinv, srcs, N);

    // layer 1 GEMM: g1 = (x@W1)*dinv -> buf0 (fp16)
    k_gemm_mfma<<<(N + 127) / 128, 256, 0, stream>>>(x, WT1, dinv, buf0, N);
    // fused: z1 = relu(agg(g1)+b1) (LDS only) ; G2 = (z1@W2)*dinv -> buf1
    k_gather_gemm<<<(N + 15) / 16, 256, 0, stream>>>(buf0, srcs, row_start, cnt, dinv, b1, WT2, buf1, N);
    // layer 2 gather: z2 = relu(agg(G2)+b2) -> buf0
    k_gather_relu<<<(N + 15) / 16, 256, 0, stream>>>(buf1, srcs, row_start, cnt, dinv, b2, buf0, N);
    // decode
    k_decode<<<(EL + 15) / 16, 256, 0, stream>>>(buf0, eli, out, EL);
}